// Round 1
// baseline (317.795 us; speedup 1.0000x reference)
//
#include <hip/hip_runtime.h>

typedef unsigned short u16;
typedef unsigned int u32;
typedef __attribute__((ext_vector_type(8))) short bf16x8;
typedef __attribute__((ext_vector_type(4))) float f32x4;

__device__ __forceinline__ u16 f2bf(float x) {
  union { float f; u32 u; } un; un.f = x;
  u32 r = un.u + 0x7FFFu + ((un.u >> 16) & 1u);
  return (u16)(r >> 16);
}

// ---------------- prep: weights->bf16, BN fold, bias gather ----------------
__global__ __launch_bounds__(256) void prep_misc(
    const float* __restrict__ Wkv, const float* __restrict__ Wq, const float* __restrict__ Wp,
    const float* __restrict__ gkv, const float* __restrict__ bkv, const float* __restrict__ mkv, const float* __restrict__ vkv,
    const float* __restrict__ gq, const float* __restrict__ bq, const float* __restrict__ mq, const float* __restrict__ vq,
    const float* __restrict__ gp, const float* __restrict__ bp, const float* __restrict__ mp, const float* __restrict__ vp,
    const float* __restrict__ ab, const int* __restrict__ bidx,
    u16* __restrict__ wkvb, u16* __restrict__ wqb, u16* __restrict__ wpb,
    float* __restrict__ skv, float* __restrict__ tkv,
    float* __restrict__ sq, float* __restrict__ tq,
    float* __restrict__ sp, float* __restrict__ tp,
    float* __restrict__ biasf)
{
  int i = blockIdx.x * 256 + threadIdx.x;
  if (i < 327680) { wkvb[i] = f2bf(Wkv[i]); return; }
  i -= 327680;
  if (i < 65536) { wqb[i] = f2bf(Wq[i]); return; }
  i -= 65536;
  if (i < 524288) { wpb[i] = f2bf(Wp[i]); return; }
  i -= 524288;
  if (i < 153664) { biasf[i] = ab[(i / 9604) * 196 + bidx[i % 9604]]; return; }
  i -= 153664;
  if (i < 1280) { float s = gkv[i] * rsqrtf(vkv[i] + 1e-5f); skv[i] = s; tkv[i] = bkv[i] - mkv[i] * s; return; }
  i -= 1280;
  if (i < 256) { float s = gq[i] * rsqrtf(vq[i] + 1e-5f); sq[i] = s; tq[i] = bq[i] - mq[i] * s; return; }
  i -= 256;
  if (i < 512) { float s = gp[i] * rsqrtf(vp[i] + 1e-5f); sp[i] = s; tp[i] = bp[i] - mp[i] * s; return; }
}

// ---------------- x (f32) -> bf16 ----------------
__global__ __launch_bounds__(256) void conv_x(const float* __restrict__ x, u16* __restrict__ xb)
{
  int u = blockIdx.x * 256 + threadIdx.x;
  float4 v = ((const float4*)x)[u];
  uint2 o;
  o.x = (u32)f2bf(v.x) | ((u32)f2bf(v.y) << 16);
  o.y = (u32)f2bf(v.z) | ((u32)f2bf(v.w) << 16);
  ((uint2*)xb)[u] = o;
}

// ---------------- generic bf16 GEMM: out = BN(A @ W^T) ----------------
// A: (M,K) bf16 row-major (optionally gathered rows), W: (N,K) bf16 row-major.
// 128x128 tile, BK=64, 4 waves, each wave a 64x64 sub-tile of 4x4 16x16x32 MFMAs.
template<int GATHER, int F32OUT>
__global__ __launch_bounds__(256) void gemm_bn(
    const u16* __restrict__ A, const u16* __restrict__ W,
    const float* __restrict__ sv, const float* __restrict__ tv,
    void* __restrict__ outp, int N, int K)
{
  __shared__ u16 As[128 * 64];
  __shared__ u16 Bs[128 * 64];
  const int tid = threadIdx.x;
  const int lane = tid & 63;
  const int wv = tid >> 6, wr = wv >> 1, wc = wv & 1;
  const int lo = lane & 15, hi = lane >> 4;
  const int m0 = blockIdx.x * 128, n0 = blockIdx.y * 128;
  f32x4 zero4 = {0.f, 0.f, 0.f, 0.f};
  f32x4 acc[4][4];
#pragma unroll
  for (int m = 0; m < 4; ++m)
#pragma unroll
    for (int n = 0; n < 4; ++n) acc[m][n] = zero4;

  for (int kt = 0; kt < K; kt += 64) {
    __syncthreads();
#pragma unroll
    for (int i = 0; i < 4; ++i) {
      int e = (i * 256 + tid) * 8;
      int r = e >> 6, c = e & 63;
      long ga;
      if (GATHER) {
        int rr = m0 + r;
        int bb = rr / 49, qi = rr - bb * 49;
        int gr = bb * 196 + (qi / 7) * 28 + (qi % 7) * 2;  // ::2 spatial subsample
        ga = (long)gr * K + (kt + c);
      } else {
        ga = (long)(m0 + r) * K + (kt + c);
      }
      *(uint4*)(As + e) = *(const uint4*)(A + ga);
      *(uint4*)(Bs + e) = *(const uint4*)(W + (long)(n0 + r) * K + (kt + c));
    }
    __syncthreads();
#pragma unroll
    for (int kk = 0; kk < 64; kk += 32) {
      bf16x8 af[4], bfr[4];
#pragma unroll
      for (int m = 0; m < 4; ++m)
        af[m] = *(const bf16x8*)(As + (wr * 64 + m * 16 + lo) * 64 + kk + hi * 8);
#pragma unroll
      for (int n = 0; n < 4; ++n)
        bfr[n] = *(const bf16x8*)(Bs + (wc * 64 + n * 16 + lo) * 64 + kk + hi * 8);
#pragma unroll
      for (int m = 0; m < 4; ++m)
#pragma unroll
        for (int n = 0; n < 4; ++n)
          acc[m][n] = __builtin_amdgcn_mfma_f32_16x16x32_bf16(af[m], bfr[n], acc[m][n], 0, 0, 0);
    }
  }
#pragma unroll
  for (int m = 0; m < 4; ++m) {
    const int row0 = m0 + wr * 64 + m * 16 + hi * 4;
#pragma unroll
    for (int n = 0; n < 4; ++n) {
      const int col = n0 + wc * 64 + n * 16 + lo;
      const float s = sv[col], t = tv[col];
#pragma unroll
      for (int j = 0; j < 4; ++j) {
        float v = acc[m][n][j] * s + t;
        long oi = (long)(row0 + j) * N + col;
        if (F32OUT) ((float*)outp)[oi] = v;
        else ((u16*)outp)[oi] = f2bf(v);
      }
    }
  }
}

// ---------------- attention: per (b,h) block ----------------
// scores = Q(49x16) @ K^T(16x196) * 0.25 + bias; softmax; O = P @ V(196x64);
// hardswish; write bf16 to hsw_o[(b*49+q)*1024 + h*64 + d].
#define KSTR 40
#define VSTR 232

__global__ __launch_bounds__(256) void attn_kernel(
    const u16* __restrict__ kv, const u16* __restrict__ qb,
    const float* __restrict__ biasf, u16* __restrict__ osw)
{
  __shared__ u16 smem[29696];
  __shared__ float rsum[64];
  u16* k_s = smem;          // [208][40], real [196][16], K-pad cols 16..31 zero
  u16* q_s = smem + 8320;   // [64][32], real [49][16]
  u16* P_s = smem;          // [64][232] bf16, aliases k_s/q_s after scores
  u16* vT  = smem + 14848;  // [64][232]: vT[d][k], rows real k<196, rest zero

  const int tid = threadIdx.x;
  const int bb = blockIdx.x >> 4, hh = blockIdx.x & 15;

  {  // zero fill all of smem (pads matter)
    u32* z = (u32*)smem;
    for (int u = tid; u < 14848; u += 256) z[u] = 0;
  }
  __syncthreads();

  const long kvbase = (long)bb * 196 * 1280 + (long)hh * 80;
  for (int u = tid; u < 196 * 8; u += 256) {  // K: [n][j] j<16
    int n = u >> 3, j2 = u & 7;
    u32 val = *(const u32*)(kv + kvbase + (long)n * 1280 + j2 * 2);
    *(u32*)(k_s + n * KSTR + j2 * 2) = val;
  }
  for (int u = tid; u < 49 * 8; u += 256) {   // Q
    int qi = u >> 3, j2 = u & 7;
    u32 val = *(const u32*)(qb + ((long)(bb * 49 + qi)) * 256 + hh * 16 + j2 * 2);
    *(u32*)(q_s + qi * 32 + j2 * 2) = val;
  }
  for (int u = tid; u < 196 * 32; u += 256) { // V transposed: vT[d][n]
    int n = u >> 5, d2 = (u & 31) * 2;
    u32 val = *(const u32*)(kv + kvbase + (long)n * 1280 + 16 + d2);
    vT[d2 * VSTR + n] = (u16)(val & 0xffffu);
    vT[(d2 + 1) * VSTR + n] = (u16)(val >> 16);
  }
  __syncthreads();

  const int wv = tid >> 6, lane = tid & 63, lo = lane & 15, hi = lane >> 4;

  // ---- scores: wave wv owns rows wv*16..wv*16+15 ----
  f32x4 sc[13];
  {
    bf16x8 aq = *(const bf16x8*)(q_s + (wv * 16 + lo) * 32 + hi * 8);
    f32x4 zero4 = {0.f, 0.f, 0.f, 0.f};
#pragma unroll
    for (int t = 0; t < 13; ++t) {
      bf16x8 bk = *(const bf16x8*)(k_s + (t * 16 + lo) * KSTR + hi * 8);
      sc[t] = __builtin_amdgcn_mfma_f32_16x16x32_bf16(aq, bk, zero4, 0, 0, 0);
    }
  }
  __syncthreads();  // all waves done reading k_s/q_s; P_s may overwrite

  {  // re-zero P pad cols 208..223 for this wave's rows (aliased stale data)
    int row = wv * 16 + (lane >> 2);
    uint2 zz; zz.x = 0; zz.y = 0;
    *(uint2*)(P_s + row * VSTR + 208 + (lane & 3) * 4) = zz;
  }

  // ---- softmax (rows distributed per C/D layout), write unnormalized P ----
#pragma unroll
  for (int j = 0; j < 4; ++j) {
    const int row = wv * 16 + hi * 4 + j;
    const bool rv = row < 49;
    float vals[13];
#pragma unroll
    for (int t = 0; t < 13; ++t) {
      int col = t * 16 + lo;
      float v = sc[t][j] * 0.25f;
      if (rv && col < 196) v += biasf[(hh * 49 + row) * 196 + col];
      else v = -1e30f;
      vals[t] = v;
    }
    float mx = vals[0];
#pragma unroll
    for (int t = 1; t < 13; ++t) mx = fmaxf(mx, vals[t]);
#pragma unroll
    for (int s = 1; s < 16; s <<= 1) mx = fmaxf(mx, __shfl_xor(mx, s, 64));
    float sum = 0.f;
#pragma unroll
    for (int t = 0; t < 13; ++t) { float p = __expf(vals[t] - mx); vals[t] = p; sum += p; }
#pragma unroll
    for (int s = 1; s < 16; s <<= 1) sum += __shfl_xor(sum, s, 64);
#pragma unroll
    for (int t = 0; t < 13; ++t) P_s[row * VSTR + t * 16 + lo] = f2bf(vals[t]);
    if (lo == 0) rsum[row] = sum;
  }
  __syncthreads();

  // ---- PV: O(64x64) = P(64x224) @ V(224x64) ----
  f32x4 oacc[4];
  {
    f32x4 zero4 = {0.f, 0.f, 0.f, 0.f};
#pragma unroll
    for (int n = 0; n < 4; ++n) oacc[n] = zero4;
  }
#pragma unroll
  for (int kt = 0; kt < 224; kt += 32) {
    bf16x8 ap = *(const bf16x8*)(P_s + (wv * 16 + lo) * VSTR + kt + hi * 8);
#pragma unroll
    for (int n = 0; n < 4; ++n) {
      bf16x8 bv = *(const bf16x8*)(vT + (n * 16 + lo) * VSTR + kt + hi * 8);
      oacc[n] = __builtin_amdgcn_mfma_f32_16x16x32_bf16(ap, bv, oacc[n], 0, 0, 0);
    }
  }
  // ---- epilogue: /sum, hardswish, store ----
#pragma unroll
  for (int j = 0; j < 4; ++j) {
    const int row = wv * 16 + hi * 4 + j;
    if (row < 49) {
      const float rinv = 1.f / rsum[row];
      const long ob = ((long)(bb * 49 + row)) * 1024 + hh * 64 + lo;
#pragma unroll
      for (int n = 0; n < 4; ++n) {
        float val = oacc[n][j] * rinv;
        float hs = val * fminf(fmaxf(val + 3.f, 0.f), 6.f) * (1.f / 6.f);
        osw[ob + n * 16] = f2bf(hs);
      }
    }
  }
}

extern "C" void kernel_launch(void* const* d_in, const int* in_sizes, int n_in,
                              void* d_out, int out_size, void* d_ws, size_t ws_size,
                              hipStream_t stream)
{
  const float* x   = (const float*)d_in[0];
  const float* Wkv = (const float*)d_in[1];
  const float* gkv = (const float*)d_in[2];
  const float* bkv = (const float*)d_in[3];
  const float* mkv = (const float*)d_in[4];
  const float* vkv = (const float*)d_in[5];
  const float* Wq  = (const float*)d_in[6];
  const float* gq  = (const float*)d_in[7];
  const float* bq  = (const float*)d_in[8];
  const float* mq  = (const float*)d_in[9];
  const float* vq  = (const float*)d_in[10];
  const float* Wp  = (const float*)d_in[11];
  const float* gp  = (const float*)d_in[12];
  const float* bp  = (const float*)d_in[13];
  const float* mp  = (const float*)d_in[14];
  const float* vp  = (const float*)d_in[15];
  const float* ab  = (const float*)d_in[16];
  const int* bidx  = (const int*)d_in[17];

  char* ws = (char*)d_ws;
  size_t off = 0;
  auto alloc = [&](size_t bytes) -> char* {
    char* p = ws + off;
    off += (bytes + 255) & ~(size_t)255;
    return p;
  };
  u16* x_bf     = (u16*)alloc((size_t)50176 * 256 * 2);
  u16* wkv_bf   = (u16*)alloc((size_t)1280 * 256 * 2);
  u16* wq_bf    = (u16*)alloc((size_t)256 * 256 * 2);
  u16* wp_bf    = (u16*)alloc((size_t)512 * 1024 * 2);
  u16* kv_buf   = (u16*)alloc((size_t)50176 * 1280 * 2);
  u16* q_buf    = (u16*)alloc((size_t)12544 * 256 * 2);
  u16* hsw      = (u16*)alloc((size_t)12544 * 1024 * 2);
  float* bias_f = (float*)alloc((size_t)153664 * 4);
  float* s_kv = (float*)alloc(1280 * 4);
  float* t_kv = (float*)alloc(1280 * 4);
  float* s_q  = (float*)alloc(256 * 4);
  float* t_q  = (float*)alloc(256 * 4);
  float* s_p  = (float*)alloc(512 * 4);
  float* t_p  = (float*)alloc(512 * 4);
  if (off > ws_size) return;  // clean failure instead of OOB writes

  prep_misc<<<4193, 256, 0, stream>>>(Wkv, Wq, Wp, gkv, bkv, mkv, vkv,
                                      gq, bq, mq, vq, gp, bp, mp, vp,
                                      ab, bidx, wkv_bf, wq_bf, wp_bf,
                                      s_kv, t_kv, s_q, t_q, s_p, t_p, bias_f);
  conv_x<<<12544, 256, 0, stream>>>(x, x_bf);
  gemm_bn<0, 0><<<dim3(392, 10), 256, 0, stream>>>(x_bf, wkv_bf, s_kv, t_kv, kv_buf, 1280, 256);
  gemm_bn<1, 0><<<dim3(98, 2), 256, 0, stream>>>(x_bf, wq_bf, s_q, t_q, q_buf, 256, 256);
  attn_kernel<<<4096, 256, 0, stream>>>(kv_buf, q_buf, bias_f, hsw);
  gemm_bn<0, 1><<<dim3(98, 4), 256, 0, stream>>>(hsw, wp_bf, s_p, t_p, d_out, 512, 1024);
}

// Round 2
// 254.015 us; speedup vs baseline: 1.2511x; 1.2511x over previous
//
#include <hip/hip_runtime.h>

typedef unsigned short u16;
typedef unsigned int u32;
typedef __attribute__((ext_vector_type(8))) short bf16x8;
typedef __attribute__((ext_vector_type(4))) float f32x4;

__device__ __forceinline__ u16 f2bf(float x) {
  union { float f; u32 u; } un; un.f = x;
  u32 r = un.u + 0x7FFFu + ((un.u >> 16) & 1u);
  return (u16)(r >> 16);
}

// ---------------- prep: weights->bf16, BN fold, bias gather, tail zero ----------------
__global__ __launch_bounds__(256) void prep_misc(
    const float* __restrict__ Wkv, const float* __restrict__ Wq, const float* __restrict__ Wp,
    const float* __restrict__ gkv, const float* __restrict__ bkv, const float* __restrict__ mkv, const float* __restrict__ vkv,
    const float* __restrict__ gq, const float* __restrict__ bq, const float* __restrict__ mq, const float* __restrict__ vq,
    const float* __restrict__ gp, const float* __restrict__ bp, const float* __restrict__ mp, const float* __restrict__ vp,
    const float* __restrict__ ab, const int* __restrict__ bidx,
    u16* __restrict__ wkvb, u16* __restrict__ wqb, u16* __restrict__ wpb,
    float* __restrict__ skv, float* __restrict__ tkv,
    float* __restrict__ sq, float* __restrict__ tq,
    float* __restrict__ sp, float* __restrict__ tp,
    float* __restrict__ biasf,
    u16* __restrict__ ktail, u16* __restrict__ vtail, u16* __restrict__ qtail)
{
  int i = blockIdx.x * 256 + threadIdx.x;
  if (i < 327680) { wkvb[i] = f2bf(Wkv[i]); return; }
  i -= 327680;
  if (i < 65536) { wqb[i] = f2bf(Wq[i]); return; }
  i -= 65536;
  if (i < 524288) { wpb[i] = f2bf(Wp[i]); return; }
  i -= 524288;
  if (i < 153664) { biasf[i] = ab[(i / 9604) * 196 + bidx[i % 9604]]; return; }
  i -= 153664;
  if (i < 1280) { float s = gkv[i] * rsqrtf(vkv[i] + 1e-5f); skv[i] = s; tkv[i] = bkv[i] - mkv[i] * s; return; }
  i -= 1280;
  if (i < 256) { float s = gq[i] * rsqrtf(vq[i] + 1e-5f); sq[i] = s; tq[i] = bq[i] - mq[i] * s; return; }
  i -= 256;
  if (i < 512) { float s = gp[i] * rsqrtf(vp[i] + 1e-5f); sp[i] = s; tp[i] = bp[i] - mp[i] * s; return; }
  i -= 512;
  if (i < 256) { ktail[i] = 0; return; }   // finite pad past k_buf (OOB frag reads)
  i -= 256;
  if (i < 64) { vtail[i] = 0; return; }    // finite pad past vT_buf
  i -= 64;
  if (i < 256) { qtail[i] = 0; return; }   // finite pad past q_buf
}

// ---------------- x (f32) -> bf16 ----------------
__global__ __launch_bounds__(256) void conv_x(const float* __restrict__ x, u16* __restrict__ xb)
{
  int u = blockIdx.x * 256 + threadIdx.x;
  float4 v = ((const float4*)x)[u];
  uint2 o;
  o.x = (u32)f2bf(v.x) | ((u32)f2bf(v.y) << 16);
  o.y = (u32)f2bf(v.z) | ((u32)f2bf(v.w) << 16);
  ((uint2*)xb)[u] = o;
}

// ---------------- generic bf16 GEMM: out = BN(A @ W^T) ----------------
// A: (M,K) bf16 row-major (optionally gathered rows), W: (N,K) bf16 row-major.
// 128x128 tile, BK=64, 4 waves, each wave 64x64 of 4x4 16x16x32 MFMAs.
// EPI: 1 = f32 row-major (p-proj), 2 = kv split K/vT layouts, 3 = q per-head layout.
template<int GATHER, int EPI>
__global__ __launch_bounds__(256) void gemm_bn(
    const u16* __restrict__ A, const u16* __restrict__ W,
    const float* __restrict__ sv, const float* __restrict__ tv,
    void* __restrict__ out1, u16* __restrict__ out2, int N, int K)
{
  __shared__ u16 As[128 * 64];
  __shared__ u16 Bs[128 * 64];
  const int tid = threadIdx.x;
  const int lane = tid & 63;
  const int wv = tid >> 6, wr = wv >> 1, wc = wv & 1;
  const int lo = lane & 15, hi = lane >> 4;
  const int m0 = blockIdx.x * 128, n0 = blockIdx.y * 128;
  f32x4 zero4 = {0.f, 0.f, 0.f, 0.f};
  f32x4 acc[4][4];
#pragma unroll
  for (int m = 0; m < 4; ++m)
#pragma unroll
    for (int n = 0; n < 4; ++n) acc[m][n] = zero4;

  for (int kt = 0; kt < K; kt += 64) {
    __syncthreads();
#pragma unroll
    for (int i = 0; i < 4; ++i) {
      int e = (i * 256 + tid) * 8;
      int r = e >> 6, c = e & 63;
      long ga;
      if (GATHER) {
        int rr = m0 + r;
        int bb = rr / 49, qi = rr - bb * 49;
        int gr = bb * 196 + (qi / 7) * 28 + (qi % 7) * 2;  // ::2 spatial subsample
        ga = (long)gr * K + (kt + c);
      } else {
        ga = (long)(m0 + r) * K + (kt + c);
      }
      *(uint4*)(As + e) = *(const uint4*)(A + ga);
      *(uint4*)(Bs + e) = *(const uint4*)(W + (long)(n0 + r) * K + (kt + c));
    }
    __syncthreads();
#pragma unroll
    for (int kk = 0; kk < 64; kk += 32) {
      bf16x8 af[4], bfr[4];
#pragma unroll
      for (int m = 0; m < 4; ++m)
        af[m] = *(const bf16x8*)(As + (wr * 64 + m * 16 + lo) * 64 + kk + hi * 8);
#pragma unroll
      for (int n = 0; n < 4; ++n)
        bfr[n] = *(const bf16x8*)(Bs + (wc * 64 + n * 16 + lo) * 64 + kk + hi * 8);
#pragma unroll
      for (int m = 0; m < 4; ++m)
#pragma unroll
        for (int n = 0; n < 4; ++n)
          acc[m][n] = __builtin_amdgcn_mfma_f32_16x16x32_bf16(af[m], bfr[n], acc[m][n], 0, 0, 0);
    }
  }
#pragma unroll
  for (int m = 0; m < 4; ++m) {
    const int row0 = m0 + wr * 64 + m * 16 + hi * 4;
#pragma unroll
    for (int n = 0; n < 4; ++n) {
      const int col = n0 + wc * 64 + n * 16 + lo;
      const float s = sv[col], t = tv[col];
#pragma unroll
      for (int j = 0; j < 4; ++j) {
        float v = acc[m][n][j] * s + t;
        const int row = row0 + j;
        if (EPI == 1) {
          ((float*)out1)[(long)row * N + col] = v;
        } else if (EPI == 2) {
          // row = b*196+n, col = h*80+cj; cj<16 -> K[b,h][n][cj]; else vT[b,h][cj-16][n]
          int b = row / 196, nn = row - b * 196;
          int h = col / 80, cj = col - h * 80;
          u16 bv = f2bf(v);
          if (cj < 16)
            ((u16*)out1)[((long)(b * 16 + h) * 196 + nn) * 16 + cj] = bv;
          else
            out2[((long)(b * 16 + h) * 64 + (cj - 16)) * 196 + nn] = bv;
        } else {  // EPI == 3: row = b*49+qi, col = h*16+jj -> q[b,h][qi][jj]
          int b = row / 49, qi = row - b * 49;
          int h = col >> 4, jj = col & 15;
          ((u16*)out1)[(long)(b * 16 + h) * 784 + qi * 16 + jj] = f2bf(v);
        }
      }
    }
  }
}

// ---------------- attention v2: per (b,h) block, zero staging, zero barriers ----------------
// K/Q/V fragments read directly from global (per-head contiguous slices, L1/L2-warm).
// Only P (unnormalized softmax probs) round-trips through LDS; each wave's P rows private.
#define VS 232

__global__ __launch_bounds__(256) void attn_kernel(
    const u16* __restrict__ kb, const u16* __restrict__ vtb,
    const u16* __restrict__ qb, const float* __restrict__ biasf,
    u16* __restrict__ osw)
{
  __shared__ __align__(16) u16 P_s[64 * VS];
  const int tid = threadIdx.x;
  const int bh = blockIdx.x;
  const int bb = bh >> 4, hh = bh & 15;
  const int wv = tid >> 6, lane = tid & 63, lo = lane & 15, hi = lane >> 4;

  const u16* kbase = kb + (long)bh * (196 * 16);
  const u16* vbase = vtb + (long)bh * (64 * 196);
  const u16* qbase = qb + (long)bh * (49 * 16);

  // zero P pad cols 208..223 (own wave's rows only; cols 224..231 never read)
  {
    int r = wv * 16 + (lane >> 2);
    uint2 zz; zz.x = 0; zz.y = 0;
    *(uint2*)(P_s + r * VS + 208 + (lane & 3) * 4) = zz;
  }

  // ---- scores: wave wv owns q-rows wv*16..+15; KD=16 < MFMA K=32 -> hi>=2 lanes zero ----
  f32x4 sc[13];
  {
    bf16x8 zf = {0, 0, 0, 0, 0, 0, 0, 0};
    bf16x8 aq = zf;
    if (hi < 2) aq = *(const bf16x8*)(qbase + (wv * 16 + lo) * 16 + hi * 8);
    f32x4 z4 = {0.f, 0.f, 0.f, 0.f};
#pragma unroll
    for (int t = 0; t < 13; ++t) {
      bf16x8 bk = zf;
      if (hi < 2) bk = *(const bf16x8*)(kbase + (t * 16 + lo) * 16 + hi * 8);
      sc[t] = __builtin_amdgcn_mfma_f32_16x16x32_bf16(aq, bk, z4, 0, 0, 0);
    }
  }

  // ---- softmax per C/D row; write unnormalized P to LDS; keep row-sums in regs ----
  float rs[4];
#pragma unroll
  for (int j = 0; j < 4; ++j) {
    const int row = wv * 16 + hi * 4 + j;
    const int rb = (row < 49) ? row : 0;
    float vals[13];
#pragma unroll
    for (int t = 0; t < 13; ++t) {
      const int col = t * 16 + lo;
      vals[t] = (col < 196) ? sc[t][j] * 0.25f + biasf[(hh * 49 + rb) * 196 + col] : -1e30f;
    }
    float mx = vals[0];
#pragma unroll
    for (int t = 1; t < 13; ++t) mx = fmaxf(mx, vals[t]);
#pragma unroll
    for (int s = 1; s < 16; s <<= 1) mx = fmaxf(mx, __shfl_xor(mx, s, 64));
    float sum = 0.f;
#pragma unroll
    for (int t = 0; t < 13; ++t) { float p = __expf(vals[t] - mx); vals[t] = p; sum += p; }
#pragma unroll
    for (int s = 1; s < 16; s <<= 1) sum += __shfl_xor(sum, s, 64);
#pragma unroll
    for (int t = 0; t < 13; ++t) P_s[row * VS + t * 16 + lo] = f2bf(vals[t]);
    rs[j] = sum;
  }

  // ---- PV: O(64x64) = P(64x224) @ V^T-rows(224x64), V frags direct from global ----
  f32x4 oacc[4];
  {
    f32x4 z4 = {0.f, 0.f, 0.f, 0.f};
#pragma unroll
    for (int n = 0; n < 4; ++n) oacc[n] = z4;
  }
#pragma unroll
  for (int kt = 0; kt < 224; kt += 32) {
    bf16x8 ap = *(const bf16x8*)(P_s + (wv * 16 + lo) * VS + kt + hi * 8);
#pragma unroll
    for (int n = 0; n < 4; ++n) {
      bf16x8 bv = *(const bf16x8*)(vbase + (n * 16 + lo) * 196 + kt + hi * 8);
      oacc[n] = __builtin_amdgcn_mfma_f32_16x16x32_bf16(ap, bv, oacc[n], 0, 0, 0);
    }
  }

  // ---- epilogue: /sum, hardswish, store bf16 to hsw[b*49+q][h*64+d] ----
#pragma unroll
  for (int j = 0; j < 4; ++j) {
    const int row = wv * 16 + hi * 4 + j;
    if (row < 49) {
      const float rinv = 1.f / rs[j];
      const long ob = ((long)(bb * 49 + row)) * 1024 + hh * 64 + lo;
#pragma unroll
      for (int n = 0; n < 4; ++n) {
        float val = oacc[n][j] * rinv;
        float hs = val * fminf(fmaxf(val + 3.f, 0.f), 6.f) * (1.f / 6.f);
        osw[ob + n * 16] = f2bf(hs);
      }
    }
  }
}

extern "C" void kernel_launch(void* const* d_in, const int* in_sizes, int n_in,
                              void* d_out, int out_size, void* d_ws, size_t ws_size,
                              hipStream_t stream)
{
  const float* x   = (const float*)d_in[0];
  const float* Wkv = (const float*)d_in[1];
  const float* gkv = (const float*)d_in[2];
  const float* bkv = (const float*)d_in[3];
  const float* mkv = (const float*)d_in[4];
  const float* vkv = (const float*)d_in[5];
  const float* Wq  = (const float*)d_in[6];
  const float* gq  = (const float*)d_in[7];
  const float* bq  = (const float*)d_in[8];
  const float* mq  = (const float*)d_in[9];
  const float* vq  = (const float*)d_in[10];
  const float* Wp  = (const float*)d_in[11];
  const float* gp  = (const float*)d_in[12];
  const float* bp  = (const float*)d_in[13];
  const float* mp  = (const float*)d_in[14];
  const float* vp  = (const float*)d_in[15];
  const float* ab  = (const float*)d_in[16];
  const int* bidx  = (const int*)d_in[17];

  char* ws = (char*)d_ws;
  size_t off = 0;
  auto alloc = [&](size_t bytes) -> char* {
    char* p = ws + off;
    off += (bytes + 255) & ~(size_t)255;
    return p;
  };
  u16* x_bf   = (u16*)alloc((size_t)50176 * 256 * 2);
  u16* wkv_bf = (u16*)alloc((size_t)1280 * 256 * 2);
  u16* wq_bf  = (u16*)alloc((size_t)256 * 256 * 2);
  u16* wp_bf  = (u16*)alloc((size_t)512 * 1024 * 2);
  u16* k_buf  = (u16*)alloc((size_t)4096 * 196 * 16 * 2 + 512);   // + finite tail
  u16* vT_buf = (u16*)alloc((size_t)4096 * 64 * 196 * 2 + 128);   // + finite tail
  u16* q_buf  = (u16*)alloc((size_t)4096 * 49 * 16 * 2 + 512);    // + finite tail
  u16* hsw    = (u16*)alloc((size_t)12544 * 1024 * 2);
  float* bias_f = (float*)alloc((size_t)153664 * 4);
  float* s_kv = (float*)alloc(1280 * 4);
  float* t_kv = (float*)alloc(1280 * 4);
  float* s_q  = (float*)alloc(256 * 4);
  float* t_q  = (float*)alloc(256 * 4);
  float* s_p  = (float*)alloc(512 * 4);
  float* t_p  = (float*)alloc(512 * 4);
  if (off > ws_size) return;  // clean failure instead of OOB writes

  u16* ktail = k_buf + (size_t)4096 * 196 * 16;
  u16* vtail = vT_buf + (size_t)4096 * 64 * 196;
  u16* qtail = q_buf + (size_t)4096 * 49 * 16;

  prep_misc<<<4196, 256, 0, stream>>>(Wkv, Wq, Wp, gkv, bkv, mkv, vkv,
                                      gq, bq, mq, vq, gp, bp, mp, vp,
                                      ab, bidx, wkv_bf, wq_bf, wp_bf,
                                      s_kv, t_kv, s_q, t_q, s_p, t_p, bias_f,
                                      ktail, vtail, qtail);
  conv_x<<<12544, 256, 0, stream>>>(x, x_bf);
  gemm_bn<0, 2><<<dim3(392, 10), 256, 0, stream>>>(x_bf, wkv_bf, s_kv, t_kv, k_buf, vT_buf, 1280, 256);
  gemm_bn<1, 3><<<dim3(98, 2), 256, 0, stream>>>(x_bf, wq_bf, s_q, t_q, q_buf, nullptr, 256, 256);
  attn_kernel<<<4096, 256, 0, stream>>>(k_buf, vT_buf, q_buf, bias_f, hsw);
  gemm_bn<0, 1><<<dim3(98, 4), 256, 0, stream>>>(hsw, wp_bf, s_p, t_p, d_out, nullptr, 512, 1024);
}

// Round 3
// 234.159 us; speedup vs baseline: 1.3572x; 1.0848x over previous
//
#include <hip/hip_runtime.h>

typedef unsigned short u16;
typedef unsigned int u32;
typedef __attribute__((ext_vector_type(8))) short bf16x8;
typedef __attribute__((ext_vector_type(4))) float f32x4;

__device__ __forceinline__ u16 f2bf(float x) {
  union { float f; u32 u; } un; un.f = x;
  u32 r = un.u + 0x7FFFu + ((un.u >> 16) & 1u);
  return (u16)(r >> 16);
}

// async global->LDS, 16B per lane; LDS dest must be wave-uniform base + lane*16
__device__ __forceinline__ void gl_lds16(const u16* gsrc, u16* ldst) {
  __builtin_amdgcn_global_load_lds(
      (const __attribute__((address_space(1))) void*)gsrc,
      (__attribute__((address_space(3))) void*)ldst,
      16, 0, 0);
}

// ---------------- prep: weights->bf16, BN fold, bias gather, tail zero ----------------
__global__ __launch_bounds__(256) void prep_misc(
    const float* __restrict__ Wkv, const float* __restrict__ Wq, const float* __restrict__ Wp,
    const float* __restrict__ gkv, const float* __restrict__ bkv, const float* __restrict__ mkv, const float* __restrict__ vkv,
    const float* __restrict__ gq, const float* __restrict__ bq, const float* __restrict__ mq, const float* __restrict__ vq,
    const float* __restrict__ gp, const float* __restrict__ bp, const float* __restrict__ mp, const float* __restrict__ vp,
    const float* __restrict__ ab, const int* __restrict__ bidx,
    u16* __restrict__ wkvb, u16* __restrict__ wqb, u16* __restrict__ wpb,
    float* __restrict__ skv, float* __restrict__ tkv,
    float* __restrict__ sq, float* __restrict__ tq,
    float* __restrict__ sp, float* __restrict__ tp,
    float* __restrict__ biasf,
    u16* __restrict__ ktail, u16* __restrict__ vtail, u16* __restrict__ qtail)
{
  int i = blockIdx.x * 256 + threadIdx.x;
  if (i < 327680) { wkvb[i] = f2bf(Wkv[i]); return; }
  i -= 327680;
  if (i < 65536) { wqb[i] = f2bf(Wq[i]); return; }
  i -= 65536;
  if (i < 524288) { wpb[i] = f2bf(Wp[i]); return; }
  i -= 524288;
  if (i < 153664) { biasf[i] = ab[(i / 9604) * 196 + bidx[i % 9604]]; return; }
  i -= 153664;
  if (i < 1280) { float s = gkv[i] * rsqrtf(vkv[i] + 1e-5f); skv[i] = s; tkv[i] = bkv[i] - mkv[i] * s; return; }
  i -= 1280;
  if (i < 256) { float s = gq[i] * rsqrtf(vq[i] + 1e-5f); sq[i] = s; tq[i] = bq[i] - mq[i] * s; return; }
  i -= 256;
  if (i < 512) { float s = gp[i] * rsqrtf(vp[i] + 1e-5f); sp[i] = s; tp[i] = bp[i] - mp[i] * s; return; }
  i -= 512;
  if (i < 256) { ktail[i] = 0; return; }   // finite pad past k_buf (OOB frag reads)
  i -= 256;
  if (i < 64) { vtail[i] = 0; return; }    // finite pad past vT_buf
  i -= 64;
  if (i < 256) { qtail[i] = 0; return; }   // finite pad past q_buf
}

// ---------------- x (f32) -> bf16 ----------------
__global__ __launch_bounds__(256) void conv_x(const float* __restrict__ x, u16* __restrict__ xb)
{
  int u = blockIdx.x * 256 + threadIdx.x;
  float4 v = ((const float4*)x)[u];
  uint2 o;
  o.x = (u32)f2bf(v.x) | ((u32)f2bf(v.y) << 16);
  o.y = (u32)f2bf(v.z) | ((u32)f2bf(v.w) << 16);
  ((uint2*)xb)[u] = o;
}

// ---------------- generic bf16 GEMM: out = BN(A @ W^T) ----------------
// A: (M,K) bf16 row-major (optionally gathered rows), W: (N,K) bf16 row-major.
// 128x128 tile, BK=64, 4 waves, each wave 64x64 of 4x4 16x16x32 MFMAs.
// global_load_lds (16B) staging, T2 XOR swizzle (pre-swizzled source cols,
// swizzled ds_read), optional XCD-chunked 1D grid (nwg must be %8==0).
// EPI: 1 = f32 row-major (p-proj), 2 = kv split K/vT layouts, 3 = q per-head layout.
template<int GATHER, int EPI, int NBLK, int SWZ>
__global__ __launch_bounds__(256) void gemm_bn(
    const u16* __restrict__ A, const u16* __restrict__ W,
    const float* __restrict__ sv, const float* __restrict__ tv,
    void* __restrict__ out1, u16* __restrict__ out2, int N, int K)
{
  __shared__ u16 As[128 * 64];
  __shared__ u16 Bs[128 * 64];
  const int tid = threadIdx.x;
  const int lane = tid & 63;
  const int wv = tid >> 6, wr = wv >> 1, wc = wv & 1;
  const int lo = lane & 15, hi = lane >> 4;

  int m_blk, n_blk;
  if (SWZ) {
    int bid = blockIdx.x;
    int cpx = gridDim.x >> 3;                 // blocks per XCD chunk
    int wg = (bid & 7) * cpx + (bid >> 3);    // bijective when gridDim.x % 8 == 0
    m_blk = wg / NBLK; n_blk = wg % NBLK;     // n-fastest within chunk (L2 reuse of A-tile)
  } else {
    m_blk = blockIdx.x; n_blk = blockIdx.y;
  }
  const int m0 = m_blk * 128, n0 = n_blk * 128;

  f32x4 zero4 = {0.f, 0.f, 0.f, 0.f};
  f32x4 acc[4][4];
#pragma unroll
  for (int m = 0; m < 4; ++m)
#pragma unroll
    for (int n = 0; n < 4; ++n) acc[m][n] = zero4;

  for (int kt = 0; kt < K; kt += 64) {
    __syncthreads();
#pragma unroll
    for (int i = 0; i < 4; ++i) {
      int e = (i * 256 + tid) * 8;
      int r = e >> 6, c = e & 63;
      int cs = c ^ ((r & 7) << 3);            // inverse-swizzled source column
      long ga;
      if (GATHER) {
        int rr = m0 + r;
        int bb = rr / 49, qi = rr - bb * 49;
        int gr = bb * 196 + (qi / 7) * 28 + (qi % 7) * 2;  // ::2 spatial subsample
        ga = (long)gr * K + (kt + cs);
      } else {
        ga = (long)(m0 + r) * K + (kt + cs);
      }
      gl_lds16(A + ga, As + e);
      gl_lds16(W + (long)(n0 + r) * K + (kt + cs), Bs + e);
    }
    __syncthreads();
#pragma unroll
    for (int kk = 0; kk < 64; kk += 32) {
      bf16x8 af[4], bfr[4];
#pragma unroll
      for (int m = 0; m < 4; ++m)
        af[m] = *(const bf16x8*)(As + (wr * 64 + m * 16 + lo) * 64 + ((kk + hi * 8) ^ ((lo & 7) << 3)));
#pragma unroll
      for (int n = 0; n < 4; ++n)
        bfr[n] = *(const bf16x8*)(Bs + (wc * 64 + n * 16 + lo) * 64 + ((kk + hi * 8) ^ ((lo & 7) << 3)));
#pragma unroll
      for (int m = 0; m < 4; ++m)
#pragma unroll
        for (int n = 0; n < 4; ++n)
          acc[m][n] = __builtin_amdgcn_mfma_f32_16x16x32_bf16(af[m], bfr[n], acc[m][n], 0, 0, 0);
    }
  }
#pragma unroll
  for (int m = 0; m < 4; ++m) {
    const int row0 = m0 + wr * 64 + m * 16 + hi * 4;
#pragma unroll
    for (int n = 0; n < 4; ++n) {
      const int col = n0 + wc * 64 + n * 16 + lo;
      const float s = sv[col], t = tv[col];
#pragma unroll
      for (int j = 0; j < 4; ++j) {
        float v = acc[m][n][j] * s + t;
        const int row = row0 + j;
        if (EPI == 1) {
          ((float*)out1)[(long)row * N + col] = v;
        } else if (EPI == 2) {
          // row = b*196+n, col = h*80+cj; cj<16 -> K[b,h][n][cj]; else vT[b,h][cj-16][n]
          int b = row / 196, nn = row - b * 196;
          int h = col / 80, cj = col - h * 80;
          u16 bv = f2bf(v);
          if (cj < 16)
            ((u16*)out1)[((long)(b * 16 + h) * 196 + nn) * 16 + cj] = bv;
          else
            out2[((long)(b * 16 + h) * 64 + (cj - 16)) * 196 + nn] = bv;
        } else {  // EPI == 3: row = b*49+qi, col = h*16+jj -> q[b,h][qi][jj]
          int b = row / 49, qi = row - b * 49;
          int h = col >> 4, jj = col & 15;
          ((u16*)out1)[(long)(b * 16 + h) * 784 + qi * 16 + jj] = f2bf(v);
        }
      }
    }
  }
}

// ---------------- attention v2: per (b,h) block, zero staging, zero barriers ----------------
// K/Q/V fragments read directly from global (per-head contiguous slices, L1/L2-warm).
// Only P (unnormalized softmax probs) round-trips through LDS; each wave's P rows private.
#define VS 232

__global__ __launch_bounds__(256) void attn_kernel(
    const u16* __restrict__ kb, const u16* __restrict__ vtb,
    const u16* __restrict__ qb, const float* __restrict__ biasf,
    u16* __restrict__ osw)
{
  __shared__ __align__(16) u16 P_s[64 * VS];
  const int tid = threadIdx.x;
  const int bh = blockIdx.x;
  const int bb = bh >> 4, hh = bh & 15;
  const int wv = tid >> 6, lane = tid & 63, lo = lane & 15, hi = lane >> 4;

  const u16* kbase = kb + (long)bh * (196 * 16);
  const u16* vbase = vtb + (long)bh * (64 * 196);
  const u16* qbase = qb + (long)bh * (49 * 16);

  // zero P pad cols 208..223 (own wave's rows only; cols 224..231 never read)
  {
    int r = wv * 16 + (lane >> 2);
    uint2 zz; zz.x = 0; zz.y = 0;
    *(uint2*)(P_s + r * VS + 208 + (lane & 3) * 4) = zz;
  }

  // ---- scores: wave wv owns q-rows wv*16..+15; KD=16 < MFMA K=32 -> hi>=2 lanes zero ----
  f32x4 sc[13];
  {
    bf16x8 zf = {0, 0, 0, 0, 0, 0, 0, 0};
    bf16x8 aq = zf;
    if (hi < 2) aq = *(const bf16x8*)(qbase + (wv * 16 + lo) * 16 + hi * 8);
    f32x4 z4 = {0.f, 0.f, 0.f, 0.f};
#pragma unroll
    for (int t = 0; t < 13; ++t) {
      bf16x8 bk = zf;
      if (hi < 2) bk = *(const bf16x8*)(kbase + (t * 16 + lo) * 16 + hi * 8);
      sc[t] = __builtin_amdgcn_mfma_f32_16x16x32_bf16(aq, bk, z4, 0, 0, 0);
    }
  }

  // ---- softmax per C/D row; write unnormalized P to LDS; keep row-sums in regs ----
  float rs[4];
#pragma unroll
  for (int j = 0; j < 4; ++j) {
    const int row = wv * 16 + hi * 4 + j;
    const int rb = (row < 49) ? row : 0;
    float vals[13];
#pragma unroll
    for (int t = 0; t < 13; ++t) {
      const int col = t * 16 + lo;
      vals[t] = (col < 196) ? sc[t][j] * 0.25f + biasf[(hh * 49 + rb) * 196 + col] : -1e30f;
    }
    float mx = vals[0];
#pragma unroll
    for (int t = 1; t < 13; ++t) mx = fmaxf(mx, vals[t]);
#pragma unroll
    for (int s = 1; s < 16; s <<= 1) mx = fmaxf(mx, __shfl_xor(mx, s, 64));
    float sum = 0.f;
#pragma unroll
    for (int t = 0; t < 13; ++t) { float p = __expf(vals[t] - mx); vals[t] = p; sum += p; }
#pragma unroll
    for (int s = 1; s < 16; s <<= 1) sum += __shfl_xor(sum, s, 64);
#pragma unroll
    for (int t = 0; t < 13; ++t) P_s[row * VS + t * 16 + lo] = f2bf(vals[t]);
    rs[j] = sum;
  }

  // ---- PV: O(64x64) = P(64x224) @ V^T-rows(224x64), V frags direct from global ----
  f32x4 oacc[4];
  {
    f32x4 z4 = {0.f, 0.f, 0.f, 0.f};
#pragma unroll
    for (int n = 0; n < 4; ++n) oacc[n] = z4;
  }
#pragma unroll
  for (int kt = 0; kt < 224; kt += 32) {
    bf16x8 ap = *(const bf16x8*)(P_s + (wv * 16 + lo) * VS + kt + hi * 8);
#pragma unroll
    for (int n = 0; n < 4; ++n) {
      bf16x8 bv = *(const bf16x8*)(vbase + (n * 16 + lo) * 196 + kt + hi * 8);
      oacc[n] = __builtin_amdgcn_mfma_f32_16x16x32_bf16(ap, bv, oacc[n], 0, 0, 0);
    }
  }

  // ---- epilogue: /sum, hardswish, store bf16 to hsw[b*49+q][h*64+d] ----
#pragma unroll
  for (int j = 0; j < 4; ++j) {
    const int row = wv * 16 + hi * 4 + j;
    if (row < 49) {
      const float rinv = 1.f / rs[j];
      const long ob = ((long)(bb * 49 + row)) * 1024 + hh * 64 + lo;
#pragma unroll
      for (int n = 0; n < 4; ++n) {
        float val = oacc[n][j] * rinv;
        float hs = val * fminf(fmaxf(val + 3.f, 0.f), 6.f) * (1.f / 6.f);
        osw[ob + n * 16] = f2bf(hs);
      }
    }
  }
}

extern "C" void kernel_launch(void* const* d_in, const int* in_sizes, int n_in,
                              void* d_out, int out_size, void* d_ws, size_t ws_size,
                              hipStream_t stream)
{
  const float* x   = (const float*)d_in[0];
  const float* Wkv = (const float*)d_in[1];
  const float* gkv = (const float*)d_in[2];
  const float* bkv = (const float*)d_in[3];
  const float* mkv = (const float*)d_in[4];
  const float* vkv = (const float*)d_in[5];
  const float* Wq  = (const float*)d_in[6];
  const float* gq  = (const float*)d_in[7];
  const float* bq  = (const float*)d_in[8];
  const float* mq  = (const float*)d_in[9];
  const float* vq  = (const float*)d_in[10];
  const float* Wp  = (const float*)d_in[11];
  const float* gp  = (const float*)d_in[12];
  const float* bp  = (const float*)d_in[13];
  const float* mp  = (const float*)d_in[14];
  const float* vp  = (const float*)d_in[15];
  const float* ab  = (const float*)d_in[16];
  const int* bidx  = (const int*)d_in[17];

  char* ws = (char*)d_ws;
  size_t off = 0;
  auto alloc = [&](size_t bytes) -> char* {
    char* p = ws + off;
    off += (bytes + 255) & ~(size_t)255;
    return p;
  };
  u16* x_bf   = (u16*)alloc((size_t)50176 * 256 * 2);
  u16* wkv_bf = (u16*)alloc((size_t)1280 * 256 * 2);
  u16* wq_bf  = (u16*)alloc((size_t)256 * 256 * 2);
  u16* wp_bf  = (u16*)alloc((size_t)512 * 1024 * 2);
  u16* k_buf  = (u16*)alloc((size_t)4096 * 196 * 16 * 2 + 512);   // + finite tail
  u16* vT_buf = (u16*)alloc((size_t)4096 * 64 * 196 * 2 + 128);   // + finite tail
  u16* q_buf  = (u16*)alloc((size_t)4096 * 49 * 16 * 2 + 512);    // + finite tail
  u16* hsw    = (u16*)alloc((size_t)12544 * 1024 * 2);
  float* bias_f = (float*)alloc((size_t)153664 * 4);
  float* s_kv = (float*)alloc(1280 * 4);
  float* t_kv = (float*)alloc(1280 * 4);
  float* s_q  = (float*)alloc(256 * 4);
  float* t_q  = (float*)alloc(256 * 4);
  float* s_p  = (float*)alloc(512 * 4);
  float* t_p  = (float*)alloc(512 * 4);
  if (off > ws_size) return;  // clean failure instead of OOB writes

  u16* ktail = k_buf + (size_t)4096 * 196 * 16;
  u16* vtail = vT_buf + (size_t)4096 * 64 * 196;
  u16* qtail = q_buf + (size_t)4096 * 49 * 16;

  prep_misc<<<4196, 256, 0, stream>>>(Wkv, Wq, Wp, gkv, bkv, mkv, vkv,
                                      gq, bq, mq, vq, gp, bp, mp, vp,
                                      ab, bidx, wkv_bf, wq_bf, wp_bf,
                                      s_kv, t_kv, s_q, t_q, s_p, t_p, bias_f,
                                      ktail, vtail, qtail);
  conv_x<<<12544, 256, 0, stream>>>(x, x_bf);
  // kv: M=50176 (392 m-blocks), N=1280 (10 n-blocks), XCD-chunked 1D grid
  gemm_bn<0, 2, 10, 1><<<3920, 256, 0, stream>>>(x_bf, wkv_bf, s_kv, t_kv, k_buf, vT_buf, 1280, 256);
  // q: small, keep 2D grid
  gemm_bn<1, 3, 2, 0><<<dim3(98, 2), 256, 0, stream>>>(x_bf, wq_bf, s_q, t_q, q_buf, nullptr, 256, 256);
  attn_kernel<<<4096, 256, 0, stream>>>(k_buf, vT_buf, q_buf, bias_f, hsw);
  // p: M=12544 (98), N=512 (4), XCD-chunked 1D grid
  gemm_bn<0, 1, 4, 1><<<392, 256, 0, stream>>>(hsw, wp_bf, s_p, t_p, d_out, nullptr, 512, 1024);
}

// Round 4
// 140.973 us; speedup vs baseline: 2.2543x; 1.6610x over previous
//
#include <hip/hip_runtime.h>

typedef unsigned short u16;
typedef unsigned int u32;
typedef __attribute__((ext_vector_type(8))) short bf16x8;
typedef __attribute__((ext_vector_type(4))) float f32x4;

__device__ __forceinline__ u16 f2bf(float x) {
  union { float f; u32 u; } un; un.f = x;
  u32 r = un.u + 0x7FFFu + ((un.u >> 16) & 1u);
  return (u16)(r >> 16);
}

// async global->LDS, 16B per lane; LDS dest must be wave-uniform base + lane*16
__device__ __forceinline__ void gl_lds16(const u16* gsrc, u16* ldst) {
  __builtin_amdgcn_global_load_lds(
      (const __attribute__((address_space(1))) void*)gsrc,
      (__attribute__((address_space(3))) void*)ldst,
      16, 0, 0);
}

// ---------------- prep: weights->bf16, BN fold (0.25 folded into q), bias gather ----------------
__global__ __launch_bounds__(256) void prep_misc(
    const float* __restrict__ Wkv, const float* __restrict__ Wq, const float* __restrict__ Wp,
    const float* __restrict__ gkv, const float* __restrict__ bkv, const float* __restrict__ mkv, const float* __restrict__ vkv,
    const float* __restrict__ gq, const float* __restrict__ bq, const float* __restrict__ mq, const float* __restrict__ vq,
    const float* __restrict__ gp, const float* __restrict__ bp, const float* __restrict__ mp, const float* __restrict__ vp,
    const float* __restrict__ ab, const int* __restrict__ bidx,
    u16* __restrict__ wkvb, u16* __restrict__ wqb, u16* __restrict__ wpb,
    float* __restrict__ skv, float* __restrict__ tkv,
    float* __restrict__ sq, float* __restrict__ tq,
    float* __restrict__ sp, float* __restrict__ tp,
    float* __restrict__ biasf)
{
  int i = blockIdx.x * 256 + threadIdx.x;
  if (i < 327680) { wkvb[i] = f2bf(Wkv[i]); return; }
  i -= 327680;
  if (i < 65536) { wqb[i] = f2bf(Wq[i]); return; }
  i -= 65536;
  if (i < 524288) { wpb[i] = f2bf(Wp[i]); return; }
  i -= 524288;
  if (i < 153664) { biasf[i] = ab[(i / 9604) * 196 + bidx[i % 9604]]; return; }
  i -= 153664;
  if (i < 1280) { float s = gkv[i] * rsqrtf(vkv[i] + 1e-5f); skv[i] = s; tkv[i] = bkv[i] - mkv[i] * s; return; }
  i -= 1280;
  if (i < 256) { float s = gq[i] * rsqrtf(vq[i] + 1e-5f); sq[i] = s * 0.25f; tq[i] = (bq[i] - mq[i] * s) * 0.25f; return; }
  i -= 256;
  if (i < 512) { float s = gp[i] * rsqrtf(vp[i] + 1e-5f); sp[i] = s; tp[i] = bp[i] - mp[i] * s; return; }
}

// ---------------- x (f32) -> bf16 ----------------
__global__ __launch_bounds__(256) void conv_x(const float* __restrict__ x, u16* __restrict__ xb)
{
  int u = blockIdx.x * 256 + threadIdx.x;
  float4 v = ((const float4*)x)[u];
  uint2 o;
  o.x = (u32)f2bf(v.x) | ((u32)f2bf(v.y) << 16);
  o.y = (u32)f2bf(v.z) | ((u32)f2bf(v.w) << 16);
  ((uint2*)xb)[u] = o;
}

// ---------------- p-proj GEMM: out = BN(A @ W^T), f32 row-major out ----------------
__global__ __launch_bounds__(256) void gemm_bn(
    const u16* __restrict__ A, const u16* __restrict__ W,
    const float* __restrict__ sv, const float* __restrict__ tv,
    float* __restrict__ outp, int N, int K, int NBLK)
{
  __shared__ u16 As[128 * 64];
  __shared__ u16 Bs[128 * 64];
  const int tid = threadIdx.x;
  const int lane = tid & 63;
  const int wv = tid >> 6, wr = wv >> 1, wc = wv & 1;
  const int lo = lane & 15, hi = lane >> 4;

  int bid = blockIdx.x;
  int cpx = gridDim.x >> 3;
  int wg = (bid & 7) * cpx + (bid >> 3);
  const int m0 = (wg / NBLK) * 128, n0 = (wg % NBLK) * 128;

  f32x4 zero4 = {0.f, 0.f, 0.f, 0.f};
  f32x4 acc[4][4];
#pragma unroll
  for (int m = 0; m < 4; ++m)
#pragma unroll
    for (int n = 0; n < 4; ++n) acc[m][n] = zero4;

  for (int kt = 0; kt < K; kt += 64) {
    __syncthreads();
#pragma unroll
    for (int i = 0; i < 4; ++i) {
      int e = (i * 256 + tid) * 8;
      int r = e >> 6, c = e & 63;
      int cs = c ^ ((r & 7) << 3);
      gl_lds16(A + (long)(m0 + r) * K + (kt + cs), As + e);
      gl_lds16(W + (long)(n0 + r) * K + (kt + cs), Bs + e);
    }
    __syncthreads();
#pragma unroll
    for (int kk = 0; kk < 64; kk += 32) {
      bf16x8 af[4], bfr[4];
#pragma unroll
      for (int m = 0; m < 4; ++m)
        af[m] = *(const bf16x8*)(As + (wr * 64 + m * 16 + lo) * 64 + ((kk + hi * 8) ^ ((lo & 7) << 3)));
#pragma unroll
      for (int n = 0; n < 4; ++n)
        bfr[n] = *(const bf16x8*)(Bs + (wc * 64 + n * 16 + lo) * 64 + ((kk + hi * 8) ^ ((lo & 7) << 3)));
#pragma unroll
      for (int m = 0; m < 4; ++m)
#pragma unroll
        for (int n = 0; n < 4; ++n)
          acc[m][n] = __builtin_amdgcn_mfma_f32_16x16x32_bf16(af[m], bfr[n], acc[m][n], 0, 0, 0);
    }
  }
#pragma unroll
  for (int m = 0; m < 4; ++m) {
    const int row0 = m0 + wr * 64 + m * 16 + hi * 4;
#pragma unroll
    for (int n = 0; n < 4; ++n) {
      const int col = n0 + wc * 64 + n * 16 + lo;
      const float s = sv[col], t = tv[col];
#pragma unroll
      for (int j = 0; j < 4; ++j)
        outp[(long)(row0 + j) * N + col] = acc[m][n][j] * s + t;
    }
  }
}

// ---------------- fused kv-proj + q-proj + attention, one block per (b,h) ----------------
// LDS map (u16 offsets), regions alias across barrier-separated phases:
//   staging: x_s [0..13312) 208x64, W_s [13312..19456) 96x64 (80 kv + 16 q rows)
//   post-GEMM: vT [0..14848) 64x232, K_s [14848..19840) 208x24, Q_s [19840..21376) 64x24
//   post-QK^T: P_s [14848..29696) 64x232 (aliases K_s/Q_s)
#define XU   13312
#define WOFF 13312
#define VTS  232
#define K_OFF 14848
#define KS   24
#define Q_OFF 19840
#define QS   24
#define P_OFF 14848
#define PS   232
#define SMEM_N 29696

__global__ __launch_bounds__(256) void fused_attn(
    const u16* __restrict__ xb, const u16* __restrict__ wkvb, const u16* __restrict__ wqb,
    const float* __restrict__ skv, const float* __restrict__ tkv,
    const float* __restrict__ sqv, const float* __restrict__ tqv,
    const float* __restrict__ biasf, u16* __restrict__ osw)
{
  __shared__ __align__(16) u16 sm[SMEM_N];
  const int tid = threadIdx.x;
  const int bid = blockIdx.x;
  const int wg = (bid & 7) * 512 + (bid >> 3);   // XCD chunk: 32 images per XCD
  const int bb = wg >> 4, hh = wg & 15;
  const int w = tid >> 6, lane = tid & 63, lo = lane & 15, hi = lane >> 4;

  const u16* xbase = xb + (long)bb * 196 * 256;
  const u16* wkvh = wkvb + (long)hh * 80 * 256;
  const u16* wqh  = wqb + (long)hh * 16 * 256;

  const int NM = (w == 0) ? 4 : 3;   // kv m-frags per wave: {0,4,8,12},{1,5,9},{2,6,10},{3,7,11}
  f32x4 z4 = {0.f, 0.f, 0.f, 0.f};
  f32x4 acc[4][5];
#pragma unroll
  for (int u = 0; u < 4; ++u)
#pragma unroll
    for (int nf = 0; nf < 5; ++nf) acc[u][nf] = z4;
  f32x4 qacc = z4;

  // q A-frag gather row (::2 spatial subsample), clamped
  int qi = w * 16 + lo; if (qi > 48) qi = 48;
  const int gr = (qi / 7) * 28 + (qi % 7) * 2;

  // ---- phase 1: KV + Q projection over K=256 in 4 chunks ----
  for (int kt = 0; kt < 256; kt += 64) {
    __syncthreads();
#pragma unroll
    for (int i = 0; i < 7; ++i) {       // x: 208x64, 6.5 wave-rounds
      if (i < 6 || tid < 128) {
        int e = (i * 256 + tid) * 8;
        int r = e >> 6, c = e & 63;
        int xr = (r < 196) ? r : 195;   // finite dup rows for pad
        int cs = c ^ ((r & 7) << 3);
        gl_lds16(xbase + (long)xr * 256 + kt + cs, sm + e);
      }
    }
#pragma unroll
    for (int i = 0; i < 3; ++i) {       // W: 96x64 exact
      int e = (i * 256 + tid) * 8;
      int r = e >> 6, c = e & 63;
      int cs = c ^ ((r & 7) << 3);
      const u16* src = (r < 80) ? (wkvh + (long)r * 256 + kt + cs)
                                : (wqh + (long)(r - 80) * 256 + kt + cs);
      gl_lds16(src, sm + WOFF + e);
    }
    __syncthreads();
#pragma unroll
    for (int kk = 0; kk < 64; kk += 32) {
      bf16x8 bfr[6];
#pragma unroll
      for (int nf = 0; nf < 6; ++nf)
        bfr[nf] = *(const bf16x8*)(sm + WOFF + (nf * 16 + lo) * 64 + ((kk + hi * 8) ^ ((lo & 7) << 3)));
      {
        bf16x8 aqf = *(const bf16x8*)(sm + gr * 64 + ((kk + hi * 8) ^ ((gr & 7) << 3)));
        qacc = __builtin_amdgcn_mfma_f32_16x16x32_bf16(aqf, bfr[5], qacc, 0, 0, 0);
      }
#pragma unroll
      for (int u = 0; u < 4; ++u) {
        if (u < NM) {
          const int mf = w + u * 4;
          bf16x8 af = *(const bf16x8*)(sm + (mf * 16 + lo) * 64 + ((kk + hi * 8) ^ ((lo & 7) << 3)));
#pragma unroll
          for (int nf = 0; nf < 5; ++nf)
            acc[u][nf] = __builtin_amdgcn_mfma_f32_16x16x32_bf16(af, bfr[nf], acc[u][nf], 0, 0, 0);
        }
      }
    }
  }
  __syncthreads();   // staging dead; aliased K/vT/Q writes may begin

  // ---- phase-1 epilogue: BN + scatter to K_s / vT / Q_s (LDS) ----
#pragma unroll
  for (int u = 0; u < 4; ++u) {
    if (u < NM) {
      const int mf = w + u * 4;
#pragma unroll
      for (int nf = 0; nf < 5; ++nf) {
        const int col = nf * 16 + lo;
        const float s = skv[hh * 80 + col], t = tkv[hh * 80 + col];
#pragma unroll
        for (int j = 0; j < 4; ++j) {
          const int nn = mf * 16 + hi * 4 + j;
          const u16 bv = f2bf(acc[u][nf][j] * s + t);
          if (col < 16) sm[K_OFF + nn * KS + col] = bv;
          else          sm[(col - 16) * VTS + nn] = bv;
        }
      }
    }
  }
  {
    const float s = sqv[hh * 16 + lo], t = tqv[hh * 16 + lo];
#pragma unroll
    for (int j = 0; j < 4; ++j) {
      const int r = w * 16 + hi * 4 + j;
      sm[Q_OFF + r * QS + lo] = f2bf(qacc[j] * s + t);
    }
  }
  __syncthreads();

  // ---- phase 2: QK^T (scale pre-folded into Q) ----
  f32x4 sc[13];
  {
    bf16x8 zf = {0, 0, 0, 0, 0, 0, 0, 0};
    bf16x8 aq2 = zf;
    if (hi < 2) aq2 = *(const bf16x8*)(sm + Q_OFF + (w * 16 + lo) * QS + hi * 8);
#pragma unroll
    for (int t13 = 0; t13 < 13; ++t13) {
      bf16x8 bk = zf;
      if (hi < 2) bk = *(const bf16x8*)(sm + K_OFF + (t13 * 16 + lo) * KS + hi * 8);
      sc[t13] = __builtin_amdgcn_mfma_f32_16x16x32_bf16(aq2, bk, z4, 0, 0, 0);
    }
  }
  __syncthreads();   // all K/Q reads done; P (aliasing K/Q) may be written

  // P pad cols 208..223 zero (own wave's rows)
  {
    const int r = w * 16 + (lane >> 2);
    uint2 zz; zz.x = 0; zz.y = 0;
    *(uint2*)(sm + P_OFF + r * PS + 208 + (lane & 3) * 4) = zz;
  }

  // ---- softmax per C/D row; unnormalized P -> LDS; row-sums in regs ----
  float rs[4];
#pragma unroll
  for (int j = 0; j < 4; ++j) {
    const int row = w * 16 + hi * 4 + j;
    const int rb = (row < 49) ? row : 0;
    float vals[13];
#pragma unroll
    for (int t = 0; t < 13; ++t) {
      const int col = t * 16 + lo;
      vals[t] = (col < 196) ? sc[t][j] + biasf[(hh * 49 + rb) * 196 + col] : -1e30f;
    }
    float mx = vals[0];
#pragma unroll
    for (int t = 1; t < 13; ++t) mx = fmaxf(mx, vals[t]);
#pragma unroll
    for (int s = 1; s < 16; s <<= 1) mx = fmaxf(mx, __shfl_xor(mx, s, 64));
    float sum = 0.f;
#pragma unroll
    for (int t = 0; t < 13; ++t) { float p = __expf(vals[t] - mx); vals[t] = p; sum += p; }
#pragma unroll
    for (int s = 1; s < 16; s <<= 1) sum += __shfl_xor(sum, s, 64);
#pragma unroll
    for (int t = 0; t < 13; ++t) sm[P_OFF + row * PS + t * 16 + lo] = f2bf(vals[t]);
    rs[j] = sum;
  }

  // ---- PV: O(64x64) = P(64x224) @ vT-rows; P rows private per wave ----
  f32x4 oacc[4];
#pragma unroll
  for (int n = 0; n < 4; ++n) oacc[n] = z4;
#pragma unroll
  for (int kt = 0; kt < 224; kt += 32) {
    bf16x8 ap = *(const bf16x8*)(sm + P_OFF + (w * 16 + lo) * PS + kt + hi * 8);
#pragma unroll
    for (int n = 0; n < 4; ++n) {
      bf16x8 bv = *(const bf16x8*)(sm + (n * 16 + lo) * VTS + kt + hi * 8);
      oacc[n] = __builtin_amdgcn_mfma_f32_16x16x32_bf16(ap, bv, oacc[n], 0, 0, 0);
    }
  }

  // ---- epilogue: /sum, hardswish, store bf16 to hsw[b*49+q][h*64+d] ----
#pragma unroll
  for (int j = 0; j < 4; ++j) {
    const int row = w * 16 + hi * 4 + j;
    if (row < 49) {
      const float rinv = 1.f / rs[j];
      const long ob = ((long)(bb * 49 + row)) * 1024 + hh * 64 + lo;
#pragma unroll
      for (int n = 0; n < 4; ++n) {
        float val = oacc[n][j] * rinv;
        float hs = val * fminf(fmaxf(val + 3.f, 0.f), 6.f) * (1.f / 6.f);
        osw[ob + n * 16] = f2bf(hs);
      }
    }
  }
}

extern "C" void kernel_launch(void* const* d_in, const int* in_sizes, int n_in,
                              void* d_out, int out_size, void* d_ws, size_t ws_size,
                              hipStream_t stream)
{
  const float* x   = (const float*)d_in[0];
  const float* Wkv = (const float*)d_in[1];
  const float* gkv = (const float*)d_in[2];
  const float* bkv = (const float*)d_in[3];
  const float* mkv = (const float*)d_in[4];
  const float* vkv = (const float*)d_in[5];
  const float* Wq  = (const float*)d_in[6];
  const float* gq  = (const float*)d_in[7];
  const float* bq  = (const float*)d_in[8];
  const float* mq  = (const float*)d_in[9];
  const float* vq  = (const float*)d_in[10];
  const float* Wp  = (const float*)d_in[11];
  const float* gp  = (const float*)d_in[12];
  const float* bp  = (const float*)d_in[13];
  const float* mp  = (const float*)d_in[14];
  const float* vp  = (const float*)d_in[15];
  const float* ab  = (const float*)d_in[16];
  const int* bidx  = (const int*)d_in[17];

  char* ws = (char*)d_ws;
  size_t off = 0;
  auto alloc = [&](size_t bytes) -> char* {
    char* p = ws + off;
    off += (bytes + 255) & ~(size_t)255;
    return p;
  };
  u16* x_bf   = (u16*)alloc((size_t)50176 * 256 * 2);
  u16* wkv_bf = (u16*)alloc((size_t)1280 * 256 * 2);
  u16* wq_bf  = (u16*)alloc((size_t)256 * 256 * 2);
  u16* wp_bf  = (u16*)alloc((size_t)512 * 1024 * 2);
  u16* hsw    = (u16*)alloc((size_t)12544 * 1024 * 2);
  float* bias_f = (float*)alloc((size_t)153664 * 4);
  float* s_kv = (float*)alloc(1280 * 4);
  float* t_kv = (float*)alloc(1280 * 4);
  float* s_q  = (float*)alloc(256 * 4);
  float* t_q  = (float*)alloc(256 * 4);
  float* s_p  = (float*)alloc(512 * 4);
  float* t_p  = (float*)alloc(512 * 4);
  if (off > ws_size) return;  // clean failure instead of OOB writes

  prep_misc<<<4193, 256, 0, stream>>>(Wkv, Wq, Wp, gkv, bkv, mkv, vkv,
                                      gq, bq, mq, vq, gp, bp, mp, vp,
                                      ab, bidx, wkv_bf, wq_bf, wp_bf,
                                      s_kv, t_kv, s_q, t_q, s_p, t_p, bias_f);
  conv_x<<<12544, 256, 0, stream>>>(x, x_bf);
  // fused kv+q+attention: 4096 blocks = 8 XCD chunks x 512 (32 images x 16 heads)
  fused_attn<<<4096, 256, 0, stream>>>(x_bf, wkv_bf, wq_bf, s_kv, t_kv, s_q, t_q, bias_f, hsw);
  // p-proj: M=12544 (98 m-blocks), N=512 (4 n-blocks), XCD-chunked 1D grid
  gemm_bn<<<392, 256, 0, stream>>>(hsw, wp_bf, s_p, t_p, (float*)d_out, 512, 1024, 4);
}

// Round 5
// 126.207 us; speedup vs baseline: 2.5180x; 1.1170x over previous
//
#include <hip/hip_runtime.h>

typedef unsigned short u16;
typedef unsigned int u32;
typedef __attribute__((ext_vector_type(8))) short bf16x8;
typedef __attribute__((ext_vector_type(4))) float f32x4;

__device__ __forceinline__ u16 f2bf(float x) {
  union { float f; u32 u; } un; un.f = x;
  u32 r = un.u + 0x7FFFu + ((un.u >> 16) & 1u);
  return (u16)(r >> 16);
}

// async global->LDS, 16B per lane; LDS dest must be wave-uniform base + lane*16
__device__ __forceinline__ void gl_lds16(const u16* gsrc, u16* ldst) {
  __builtin_amdgcn_global_load_lds(
      (const __attribute__((address_space(1))) void*)gsrc,
      (__attribute__((address_space(3))) void*)ldst,
      16, 0, 0);
}

// ---------------- prep: weights->bf16, BN fold (0.25 folded into q), bias gather ----------------
__global__ __launch_bounds__(256) void prep_misc(
    const float* __restrict__ Wkv, const float* __restrict__ Wq, const float* __restrict__ Wp,
    const float* __restrict__ gkv, const float* __restrict__ bkv, const float* __restrict__ mkv, const float* __restrict__ vkv,
    const float* __restrict__ gq, const float* __restrict__ bq, const float* __restrict__ mq, const float* __restrict__ vq,
    const float* __restrict__ gp, const float* __restrict__ bp, const float* __restrict__ mp, const float* __restrict__ vp,
    const float* __restrict__ ab, const int* __restrict__ bidx,
    u16* __restrict__ wkvb, u16* __restrict__ wqb, u16* __restrict__ wpb,
    float* __restrict__ skv, float* __restrict__ tkv,
    float* __restrict__ sq, float* __restrict__ tq,
    float* __restrict__ sp, float* __restrict__ tp,
    float* __restrict__ biasf)
{
  int i = blockIdx.x * 256 + threadIdx.x;
  if (i < 327680) { wkvb[i] = f2bf(Wkv[i]); return; }
  i -= 327680;
  if (i < 65536) { wqb[i] = f2bf(Wq[i]); return; }
  i -= 65536;
  if (i < 524288) { wpb[i] = f2bf(Wp[i]); return; }
  i -= 524288;
  if (i < 153664) { biasf[i] = ab[(i / 9604) * 196 + bidx[i % 9604]]; return; }
  i -= 153664;
  if (i < 1280) { float s = gkv[i] * rsqrtf(vkv[i] + 1e-5f); skv[i] = s; tkv[i] = bkv[i] - mkv[i] * s; return; }
  i -= 1280;
  if (i < 256) { float s = gq[i] * rsqrtf(vq[i] + 1e-5f); sq[i] = s * 0.25f; tq[i] = (bq[i] - mq[i] * s) * 0.25f; return; }
  i -= 256;
  if (i < 512) { float s = gp[i] * rsqrtf(vp[i] + 1e-5f); sp[i] = s; tp[i] = bp[i] - mp[i] * s; return; }
}

// ---------------- x (f32) -> bf16 ----------------
__global__ __launch_bounds__(256) void conv_x(const float* __restrict__ x, u16* __restrict__ xb)
{
  int u = blockIdx.x * 256 + threadIdx.x;
  float4 v = ((const float4*)x)[u];
  uint2 o;
  o.x = (u32)f2bf(v.x) | ((u32)f2bf(v.y) << 16);
  o.y = (u32)f2bf(v.z) | ((u32)f2bf(v.w) << 16);
  ((uint2*)xb)[u] = o;
}

// ---------------- p-proj GEMM: out = BN(A @ W^T), f32 row-major out ----------------
__global__ __launch_bounds__(256) void gemm_bn(
    const u16* __restrict__ A, const u16* __restrict__ W,
    const float* __restrict__ sv, const float* __restrict__ tv,
    float* __restrict__ outp, int N, int K, int NBLK)
{
  __shared__ u16 As[128 * 64];
  __shared__ u16 Bs[128 * 64];
  const int tid = threadIdx.x;
  const int lane = tid & 63;
  const int wv = tid >> 6, wr = wv >> 1, wc = wv & 1;
  const int lo = lane & 15, hi = lane >> 4;

  int bid = blockIdx.x;
  int cpx = gridDim.x >> 3;
  int wg = (bid & 7) * cpx + (bid >> 3);
  const int m0 = (wg / NBLK) * 128, n0 = (wg % NBLK) * 128;

  f32x4 zero4 = {0.f, 0.f, 0.f, 0.f};
  f32x4 acc[4][4];
#pragma unroll
  for (int m = 0; m < 4; ++m)
#pragma unroll
    for (int n = 0; n < 4; ++n) acc[m][n] = zero4;

  for (int kt = 0; kt < K; kt += 64) {
    __syncthreads();
#pragma unroll
    for (int i = 0; i < 4; ++i) {
      int e = (i * 256 + tid) * 8;
      int r = e >> 6, c = e & 63;
      int cs = c ^ ((r & 7) << 3);
      gl_lds16(A + (long)(m0 + r) * K + (kt + cs), As + e);
      gl_lds16(W + (long)(n0 + r) * K + (kt + cs), Bs + e);
    }
    __syncthreads();
#pragma unroll
    for (int kk = 0; kk < 64; kk += 32) {
      bf16x8 af[4], bfr[4];
#pragma unroll
      for (int m = 0; m < 4; ++m)
        af[m] = *(const bf16x8*)(As + (wr * 64 + m * 16 + lo) * 64 + ((kk + hi * 8) ^ ((lo & 7) << 3)));
#pragma unroll
      for (int n = 0; n < 4; ++n)
        bfr[n] = *(const bf16x8*)(Bs + (wc * 64 + n * 16 + lo) * 64 + ((kk + hi * 8) ^ ((lo & 7) << 3)));
#pragma unroll
      for (int m = 0; m < 4; ++m)
#pragma unroll
        for (int n = 0; n < 4; ++n)
          acc[m][n] = __builtin_amdgcn_mfma_f32_16x16x32_bf16(af[m], bfr[n], acc[m][n], 0, 0, 0);
    }
  }
#pragma unroll
  for (int m = 0; m < 4; ++m) {
    const int row0 = m0 + wr * 64 + m * 16 + hi * 4;
#pragma unroll
    for (int n = 0; n < 4; ++n) {
      const int col = n0 + wc * 64 + n * 16 + lo;
      const float s = sv[col], t = tv[col];
#pragma unroll
      for (int j = 0; j < 4; ++j)
        outp[(long)(row0 + j) * N + col] = acc[m][n][j] * s + t;
    }
  }
}

// ---------------- fused kv-proj + q-proj + attention, one block per (b,h) ----------------
// LDS map (u16 offsets), regions alias across barrier-separated phases:
//   phase1 staging: x_s [0..13312) 208x64, W_s [13312..19456) 96x64 (80 kv + 16 q rows)
//   post-GEMM:      vT  [0..13312) 64 rows x 208 cols (aliases x_s, EXACT fit),
//                   K_s [13312..18304) 208x24, Q_s [18304..19840) 64x24
//   post-QK^T:      P_s [13312..26624) 64x208 (aliases K_s/Q_s)
// Total 26624 u16 = 53248 B -> 3 blocks/CU.
#define WOFF  13312
#define VTS   208
#define KOFF  13312
#define KS    24
#define QOFF  18304
#define QS    24
#define POFF  13312
#define PS    208
#define SMEM_N 26624

// range-safe XOR swizzle for stride-208 tiles: permutes within 64-col blocks,
// identity on the 16-wide tail (cols 192..207) where XOR keys would escape.
__device__ __forceinline__ int swz(int col, int rowkey) {
  return (col < 192) ? (col ^ ((rowkey & 7) << 3)) : col;
}

__global__ __launch_bounds__(256, 3) void fused_attn(
    const u16* __restrict__ xb, const u16* __restrict__ wkvb, const u16* __restrict__ wqb,
    const float* __restrict__ skv, const float* __restrict__ tkv,
    const float* __restrict__ sqv, const float* __restrict__ tqv,
    const float* __restrict__ biasf, u16* __restrict__ osw)
{
  __shared__ __align__(16) u16 sm[SMEM_N];
  const int tid = threadIdx.x;
  const int bid = blockIdx.x;
  const int wg = (bid & 7) * 512 + (bid >> 3);   // XCD chunk: 32 images per XCD
  const int bb = wg >> 4, hh = wg & 15;
  const int w = tid >> 6, lane = tid & 63, lo = lane & 15, hi = lane >> 4;

  const u16* xbase = xb + (long)bb * 196 * 256;
  const u16* wkvh = wkvb + (long)hh * 80 * 256;
  const u16* wqh  = wqb + (long)hh * 16 * 256;

  const int NM = (w == 0) ? 4 : 3;   // kv m-frags per wave: {0,4,8,12},{1,5,9},{2,6,10},{3,7,11}
  f32x4 z4 = {0.f, 0.f, 0.f, 0.f};
  f32x4 acc[4][5];
#pragma unroll
  for (int u = 0; u < 4; ++u)
#pragma unroll
    for (int nf = 0; nf < 5; ++nf) acc[u][nf] = z4;
  f32x4 qacc = z4;

  // q A-frag gather row (::2 spatial subsample), clamped
  int qi = w * 16 + lo; if (qi > 48) qi = 48;
  const int gr = (qi / 7) * 28 + (qi % 7) * 2;

  // ---- phase 1: KV + Q projection over K=256 in 4 chunks ----
  for (int kt = 0; kt < 256; kt += 64) {
    __syncthreads();
#pragma unroll
    for (int i = 0; i < 7; ++i) {       // x: 208x64, 6.5 wave-rounds
      if (i < 6 || tid < 128) {
        int e = (i * 256 + tid) * 8;
        int r = e >> 6, c = e & 63;
        int xr = (r < 196) ? r : 195;   // finite dup rows for pad
        int cs = c ^ ((r & 7) << 3);
        gl_lds16(xbase + (long)xr * 256 + kt + cs, sm + e);
      }
    }
#pragma unroll
    for (int i = 0; i < 3; ++i) {       // W: 96x64 exact
      int e = (i * 256 + tid) * 8;
      int r = e >> 6, c = e & 63;
      int cs = c ^ ((r & 7) << 3);
      const u16* src = (r < 80) ? (wkvh + (long)r * 256 + kt + cs)
                                : (wqh + (long)(r - 80) * 256 + kt + cs);
      gl_lds16(src, sm + WOFF + e);
    }
    __syncthreads();
    __builtin_amdgcn_s_setprio(1);
#pragma unroll
    for (int kk = 0; kk < 64; kk += 32) {
      bf16x8 bfr[6];
#pragma unroll
      for (int nf = 0; nf < 6; ++nf)
        bfr[nf] = *(const bf16x8*)(sm + WOFF + (nf * 16 + lo) * 64 + ((kk + hi * 8) ^ ((lo & 7) << 3)));
      {
        bf16x8 aqf = *(const bf16x8*)(sm + gr * 64 + ((kk + hi * 8) ^ ((gr & 7) << 3)));
        qacc = __builtin_amdgcn_mfma_f32_16x16x32_bf16(aqf, bfr[5], qacc, 0, 0, 0);
      }
#pragma unroll
      for (int u = 0; u < 4; ++u) {
        if (u < NM) {
          const int mf = w + u * 4;
          bf16x8 af = *(const bf16x8*)(sm + (mf * 16 + lo) * 64 + ((kk + hi * 8) ^ ((lo & 7) << 3)));
#pragma unroll
          for (int nf = 0; nf < 5; ++nf)
            acc[u][nf] = __builtin_amdgcn_mfma_f32_16x16x32_bf16(af, bfr[nf], acc[u][nf], 0, 0, 0);
        }
      }
    }
    __builtin_amdgcn_s_setprio(0);
  }
  __syncthreads();   // staging dead; aliased K/vT/Q writes may begin

  // ---- phase-1 epilogue: BN + scatter to K_s / vT / Q_s (LDS) ----
#pragma unroll
  for (int u = 0; u < 4; ++u) {
    if (u < NM) {
      const int mf = w + u * 4;
#pragma unroll
      for (int nf = 0; nf < 5; ++nf) {
        const int col = nf * 16 + lo;
        const float s = skv[hh * 80 + col], t = tkv[hh * 80 + col];
#pragma unroll
        for (int j = 0; j < 4; ++j) {
          const int nn = mf * 16 + hi * 4 + j;
          const u16 bv = f2bf(acc[u][nf][j] * s + t);
          if (col < 16) sm[KOFF + nn * KS + col] = bv;
          else          sm[(col - 16) * VTS + swz(nn, col - 16)] = bv;
        }
      }
    }
  }
  {
    const float s = sqv[hh * 16 + lo], t = tqv[hh * 16 + lo];
#pragma unroll
    for (int j = 0; j < 4; ++j) {
      const int r = w * 16 + hi * 4 + j;
      sm[QOFF + r * QS + lo] = f2bf(qacc[j] * s + t);
    }
  }
  __syncthreads();

  // ---- phase 2: QK^T (scale pre-folded into Q) ----
  f32x4 sc[13];
  {
    bf16x8 zf = {0, 0, 0, 0, 0, 0, 0, 0};
    bf16x8 aq2 = zf;
    if (hi < 2) aq2 = *(const bf16x8*)(sm + QOFF + (w * 16 + lo) * QS + hi * 8);
#pragma unroll
    for (int t13 = 0; t13 < 13; ++t13) {
      bf16x8 bk = zf;
      if (hi < 2) bk = *(const bf16x8*)(sm + KOFF + (t13 * 16 + lo) * KS + hi * 8);
      sc[t13] = __builtin_amdgcn_mfma_f32_16x16x32_bf16(aq2, bk, z4, 0, 0, 0);
    }
  }
  __syncthreads();   // all K/Q reads done; P (aliasing K/Q) may be written

  // ---- softmax per C/D row; unnormalized P -> LDS (cols 0..207 all covered) ----
  float rs[4];
#pragma unroll
  for (int j = 0; j < 4; ++j) {
    const int row = w * 16 + hi * 4 + j;
    const int rb = (row < 49) ? row : 0;
    float vals[13];
#pragma unroll
    for (int t = 0; t < 13; ++t) {
      const int col = t * 16 + lo;
      vals[t] = (col < 196) ? sc[t][j] + biasf[(hh * 49 + rb) * 196 + col] : -1e30f;
    }
    float mx = vals[0];
#pragma unroll
    for (int t = 1; t < 13; ++t) mx = fmaxf(mx, vals[t]);
#pragma unroll
    for (int s = 1; s < 16; s <<= 1) mx = fmaxf(mx, __shfl_xor(mx, s, 64));
    float sum = 0.f;
#pragma unroll
    for (int t = 0; t < 13; ++t) { float p = __expf(vals[t] - mx); vals[t] = p; sum += p; }
#pragma unroll
    for (int s = 1; s < 16; s <<= 1) sum += __shfl_xor(sum, s, 64);
#pragma unroll
    for (int t = 0; t < 13; ++t) sm[POFF + row * PS + swz(t * 16 + lo, row)] = f2bf(vals[t]);
    rs[j] = sum;
  }

  // ---- PV: O(64x64) = P(64x208) @ vT-rows; P rows private per wave (no barrier) ----
  f32x4 oacc[4];
#pragma unroll
  for (int n = 0; n < 4; ++n) oacc[n] = z4;
  __builtin_amdgcn_s_setprio(1);
#pragma unroll
  for (int kt = 0; kt < 192; kt += 32) {
    bf16x8 ap = *(const bf16x8*)(sm + POFF + (w * 16 + lo) * PS + ((kt + hi * 8) ^ ((lo & 7) << 3)));
#pragma unroll
    for (int n = 0; n < 4; ++n) {
      bf16x8 bv = *(const bf16x8*)(sm + (n * 16 + lo) * VTS + ((kt + hi * 8) ^ ((lo & 7) << 3)));
      oacc[n] = __builtin_amdgcn_mfma_f32_16x16x32_bf16(ap, bv, oacc[n], 0, 0, 0);
    }
  }
  {  // tail chunk: k = 192..207, 16-wide, hi<2 guarded, no swizzle (identity region)
    bf16x8 zf = {0, 0, 0, 0, 0, 0, 0, 0};
    bf16x8 ap = zf;
    if (hi < 2) ap = *(const bf16x8*)(sm + POFF + (w * 16 + lo) * PS + 192 + hi * 8);
#pragma unroll
    for (int n = 0; n < 4; ++n) {
      bf16x8 bv = zf;
      if (hi < 2) bv = *(const bf16x8*)(sm + (n * 16 + lo) * VTS + 192 + hi * 8);
      oacc[n] = __builtin_amdgcn_mfma_f32_16x16x32_bf16(ap, bv, oacc[n], 0, 0, 0);
    }
  }
  __builtin_amdgcn_s_setprio(0);

  // ---- epilogue: /sum, hardswish, store bf16 to hsw[b*49+q][h*64+d] ----
#pragma unroll
  for (int j = 0; j < 4; ++j) {
    const int row = w * 16 + hi * 4 + j;
    if (row < 49) {
      const float rinv = 1.f / rs[j];
      const long ob = ((long)(bb * 49 + row)) * 1024 + hh * 64 + lo;
#pragma unroll
      for (int n = 0; n < 4; ++n) {
        float val = oacc[n][j] * rinv;
        float hs = val * fminf(fmaxf(val + 3.f, 0.f), 6.f) * (1.f / 6.f);
        osw[ob + n * 16] = f2bf(hs);
      }
    }
  }
}

extern "C" void kernel_launch(void* const* d_in, const int* in_sizes, int n_in,
                              void* d_out, int out_size, void* d_ws, size_t ws_size,
                              hipStream_t stream)
{
  const float* x   = (const float*)d_in[0];
  const float* Wkv = (const float*)d_in[1];
  const float* gkv = (const float*)d_in[2];
  const float* bkv = (const float*)d_in[3];
  const float* mkv = (const float*)d_in[4];
  const float* vkv = (const float*)d_in[5];
  const float* Wq  = (const float*)d_in[6];
  const float* gq  = (const float*)d_in[7];
  const float* bq  = (const float*)d_in[8];
  const float* mq  = (const float*)d_in[9];
  const float* vq  = (const float*)d_in[10];
  const float* Wp  = (const float*)d_in[11];
  const float* gp  = (const float*)d_in[12];
  const float* bp  = (const float*)d_in[13];
  const float* mp  = (const float*)d_in[14];
  const float* vp  = (const float*)d_in[15];
  const float* ab  = (const float*)d_in[16];
  const int* bidx  = (const int*)d_in[17];

  char* ws = (char*)d_ws;
  size_t off = 0;
  auto alloc = [&](size_t bytes) -> char* {
    char* p = ws + off;
    off += (bytes + 255) & ~(size_t)255;
    return p;
  };
  u16* x_bf   = (u16*)alloc((size_t)50176 * 256 * 2);
  u16* wkv_bf = (u16*)alloc((size_t)1280 * 256 * 2);
  u16* wq_bf  = (u16*)alloc((size_t)256 * 256 * 2);
  u16* wp_bf  = (u16*)alloc((size_t)512 * 1024 * 2);
  u16* hsw    = (u16*)alloc((size_t)12544 * 1024 * 2);
  float* bias_f = (float*)alloc((size_t)153664 * 4);
  float* s_kv = (float*)alloc(1280 * 4);
  float* t_kv = (float*)alloc(1280 * 4);
  float* s_q  = (float*)alloc(256 * 4);
  float* t_q  = (float*)alloc(256 * 4);
  float* s_p  = (float*)alloc(512 * 4);
  float* t_p  = (float*)alloc(512 * 4);
  if (off > ws_size) return;  // clean failure instead of OOB writes

  prep_misc<<<4193, 256, 0, stream>>>(Wkv, Wq, Wp, gkv, bkv, mkv, vkv,
                                      gq, bq, mq, vq, gp, bp, mp, vp,
                                      ab, bidx, wkv_bf, wq_bf, wp_bf,
                                      s_kv, t_kv, s_q, t_q, s_p, t_p, bias_f);
  conv_x<<<12544, 256, 0, stream>>>(x, x_bf);
  // fused kv+q+attention: 4096 blocks = 8 XCD chunks x 512 (32 images x 16 heads)
  fused_attn<<<4096, 256, 0, stream>>>(x_bf, wkv_bf, wq_bf, s_kv, t_kv, s_q, t_q, bias_f, hsw);
  // p-proj: M=12544 (98 m-blocks), N=512 (4 n-blocks), XCD-chunked 1D grid
  gemm_bn<<<392, 256, 0, stream>>>(hsw, wp_bf, s_p, t_p, (float*)d_out, 512, 1024, 4);
}

// Round 6
// 125.667 us; speedup vs baseline: 2.5289x; 1.0043x over previous
//
#include <hip/hip_runtime.h>

typedef unsigned short u16;
typedef unsigned int u32;
typedef __attribute__((ext_vector_type(8))) short bf16x8;
typedef __attribute__((ext_vector_type(4))) float f32x4;

__device__ __forceinline__ u16 f2bf(float x) {
  union { float f; u32 u; } un; un.f = x;
  u32 r = un.u + 0x7FFFu + ((un.u >> 16) & 1u);
  return (u16)(r >> 16);
}

// async global->LDS, 16B per lane; LDS dest must be wave-uniform base + lane*16
__device__ __forceinline__ void gl_lds16(const u16* gsrc, u16* ldst) {
  __builtin_amdgcn_global_load_lds(
      (const __attribute__((address_space(1))) void*)gsrc,
      (__attribute__((address_space(3))) void*)ldst,
      16, 0, 0);
}

// ---------------- prep: weights->bf16, BN fold, bias gather ----------------
// Q's stored scale/shift absorb: its own BN, SCALE=0.25, and K's BN scale sk_c
// (K is stored RAW; K's BN shift contributes only a per-q softmax-invariant const).
__global__ __launch_bounds__(256) void prep_misc(
    const float* __restrict__ Wkv, const float* __restrict__ Wq, const float* __restrict__ Wp,
    const float* __restrict__ gkv, const float* __restrict__ bkv, const float* __restrict__ mkv, const float* __restrict__ vkv,
    const float* __restrict__ gq, const float* __restrict__ bq, const float* __restrict__ mq, const float* __restrict__ vq,
    const float* __restrict__ gp, const float* __restrict__ bp, const float* __restrict__ mp, const float* __restrict__ vp,
    const float* __restrict__ ab, const int* __restrict__ bidx,
    u16* __restrict__ wkvb, u16* __restrict__ wqb, u16* __restrict__ wpb,
    float* __restrict__ skv, float* __restrict__ tkv,
    float* __restrict__ sq, float* __restrict__ tq,
    float* __restrict__ sp, float* __restrict__ tp,
    float* __restrict__ biasf)
{
  int i = blockIdx.x * 256 + threadIdx.x;
  if (i < 327680) { wkvb[i] = f2bf(Wkv[i]); return; }
  i -= 327680;
  if (i < 65536) { wqb[i] = f2bf(Wq[i]); return; }
  i -= 65536;
  if (i < 524288) { wpb[i] = f2bf(Wp[i]); return; }
  i -= 524288;
  if (i < 153664) { biasf[i] = ab[(i / 9604) * 196 + bidx[i % 9604]]; return; }
  i -= 153664;
  if (i < 1280) { float s = gkv[i] * rsqrtf(vkv[i] + 1e-5f); skv[i] = s; tkv[i] = bkv[i] - mkv[i] * s; return; }
  i -= 1280;
  if (i < 256) {
    int h = i >> 4, c = i & 15;
    float sk = gkv[h * 80 + c] * rsqrtf(vkv[h * 80 + c] + 1e-5f);
    float s = gq[i] * rsqrtf(vq[i] + 1e-5f);
    sq[i] = s * 0.25f * sk;
    tq[i] = (bq[i] - mq[i] * s) * 0.25f * sk;
    return;
  }
  i -= 256;
  if (i < 512) { float s = gp[i] * rsqrtf(vp[i] + 1e-5f); sp[i] = s; tp[i] = bp[i] - mp[i] * s; return; }
}

// ---------------- x (f32) -> bf16 ----------------
__global__ __launch_bounds__(256) void conv_x(const float* __restrict__ x, u16* __restrict__ xb)
{
  int u = blockIdx.x * 256 + threadIdx.x;
  float4 v = ((const float4*)x)[u];
  uint2 o;
  o.x = (u32)f2bf(v.x) | ((u32)f2bf(v.y) << 16);
  o.y = (u32)f2bf(v.z) | ((u32)f2bf(v.w) << 16);
  ((uint2*)xb)[u] = o;
}

// ---------------- p-proj GEMM: out = BN(A @ W^T), f32 row-major out ----------------
__global__ __launch_bounds__(256) void gemm_bn(
    const u16* __restrict__ A, const u16* __restrict__ W,
    const float* __restrict__ sv, const float* __restrict__ tv,
    float* __restrict__ outp, int N, int K, int NBLK)
{
  __shared__ u16 As[128 * 64];
  __shared__ u16 Bs[128 * 64];
  const int tid = threadIdx.x;
  const int lane = tid & 63;
  const int wv = tid >> 6, wr = wv >> 1, wc = wv & 1;
  const int lo = lane & 15, hi = lane >> 4;

  int bid = blockIdx.x;
  int cpx = gridDim.x >> 3;
  int wg = (bid & 7) * cpx + (bid >> 3);
  const int m0 = (wg / NBLK) * 128, n0 = (wg % NBLK) * 128;

  f32x4 zero4 = {0.f, 0.f, 0.f, 0.f};
  f32x4 acc[4][4];
#pragma unroll
  for (int m = 0; m < 4; ++m)
#pragma unroll
    for (int n = 0; n < 4; ++n) acc[m][n] = zero4;

  for (int kt = 0; kt < K; kt += 64) {
    __syncthreads();
#pragma unroll
    for (int i = 0; i < 4; ++i) {
      int e = (i * 256 + tid) * 8;
      int r = e >> 6, c = e & 63;
      int cs = c ^ ((r & 7) << 3);
      gl_lds16(A + (long)(m0 + r) * K + (kt + cs), As + e);
      gl_lds16(W + (long)(n0 + r) * K + (kt + cs), Bs + e);
    }
    __syncthreads();
#pragma unroll
    for (int kk = 0; kk < 64; kk += 32) {
      bf16x8 af[4], bfr[4];
#pragma unroll
      for (int m = 0; m < 4; ++m)
        af[m] = *(const bf16x8*)(As + (wr * 64 + m * 16 + lo) * 64 + ((kk + hi * 8) ^ ((lo & 7) << 3)));
#pragma unroll
      for (int n = 0; n < 4; ++n)
        bfr[n] = *(const bf16x8*)(Bs + (wc * 64 + n * 16 + lo) * 64 + ((kk + hi * 8) ^ ((lo & 7) << 3)));
#pragma unroll
      for (int m = 0; m < 4; ++m)
#pragma unroll
        for (int n = 0; n < 4; ++n)
          acc[m][n] = __builtin_amdgcn_mfma_f32_16x16x32_bf16(af[m], bfr[n], acc[m][n], 0, 0, 0);
    }
  }
#pragma unroll
  for (int m = 0; m < 4; ++m) {
    const int row0 = m0 + wr * 64 + m * 16 + hi * 4;
#pragma unroll
    for (int n = 0; n < 4; ++n) {
      const int col = n0 + wc * 64 + n * 16 + lo;
      const float s = sv[col], t = tv[col];
#pragma unroll
      for (int j = 0; j < 4; ++j)
        outp[(long)(row0 + j) * N + col] = acc[m][n][j] * s + t;
    }
  }
}

// ---------------- fused kv-proj + q-proj + attention, one block per (b,h) ----------------
// LDS map (u16 offsets), regions alias across barrier-separated phases:
//   phase1 staging: x_s [0..13312) 208x64, W_s [13312..19456) 96x64 (80 kv + 16 q rows)
//   post-GEMM:      vT  [0..13312) 64x208 RAW V (aliases x_s, exact fit),
//                   K_s [13312..18304) 208x24 RAW K, Q_s [18304..19840) 64x24 (BN+folds)
//   post-QK^T:      P_s [13312..26624) 64x208 (aliases K_s/Q_s)
// Total 26624 u16 = 53248 B -> 3 blocks/CU.
#define WOFF  13312
#define VTS   208
#define KOFF  13312
#define KS    24
#define QOFF  18304
#define QS    24
#define POFF  13312
#define PS    208
#define SMEM_N 26624

// range-safe XOR swizzle for stride-208 tiles: permutes within 64-col blocks,
// identity on the 16-wide tail (cols 192..207) where XOR keys would escape.
__device__ __forceinline__ int swz(int col, int rowkey) {
  return (col < 192) ? (col ^ ((rowkey & 7) << 3)) : col;
}

__global__ __launch_bounds__(256, 3) void fused_attn(
    const u16* __restrict__ xb, const u16* __restrict__ wkvb, const u16* __restrict__ wqb,
    const float* __restrict__ skv, const float* __restrict__ tkv,
    const float* __restrict__ sqv, const float* __restrict__ tqv,
    const float* __restrict__ biasf, u16* __restrict__ osw)
{
  __shared__ __align__(16) u16 sm[SMEM_N];
  const int tid = threadIdx.x;
  const int bid = blockIdx.x;
  const int wg = (bid & 7) * 512 + (bid >> 3);   // XCD chunk: 32 images per XCD
  const int bb = wg >> 4, hh = wg & 15;
  const int w = tid >> 6, lane = tid & 63, lo = lane & 15, hi = lane >> 4;

  const u16* xbase = xb + (long)bb * 196 * 256;
  const u16* wkvh = wkvb + (long)hh * 80 * 256;
  const u16* wqh  = wqb + (long)hh * 16 * 256;

  f32x4 z4 = {0.f, 0.f, 0.f, 0.f};
  // frags {w, w+4, w+8} x 5 nf; frag 12 split: w1 -> nf0,1; w2 -> nf2,3; w3 -> nf4
  f32x4 acc[3][5];
#pragma unroll
  for (int u = 0; u < 3; ++u)
#pragma unroll
    for (int nf = 0; nf < 5; ++nf) acc[u][nf] = z4;
  f32x4 acc12a = z4, acc12b = z4;
  f32x4 qacc = z4;

  // q A-frag gather row (::2 spatial subsample), clamped
  int qi = w * 16 + lo; if (qi > 48) qi = 48;
  const int gr = (qi / 7) * 28 + (qi % 7) * 2;

  // ---- phase 1: KV + Q projection over K=256 in 4 chunks ----
  for (int kt = 0; kt < 256; kt += 64) {
    __syncthreads();
#pragma unroll
    for (int i = 0; i < 7; ++i) {       // x: 208x64, 6.5 wave-rounds
      if (i < 6 || tid < 128) {
        int e = (i * 256 + tid) * 8;
        int r = e >> 6, c = e & 63;
        int xr = (r < 196) ? r : 195;   // finite dup rows for pad
        int cs = c ^ ((r & 7) << 3);
        gl_lds16(xbase + (long)xr * 256 + kt + cs, sm + e);
      }
    }
#pragma unroll
    for (int i = 0; i < 3; ++i) {       // W: 96x64 exact
      int e = (i * 256 + tid) * 8;
      int r = e >> 6, c = e & 63;
      int cs = c ^ ((r & 7) << 3);
      const u16* src = (r < 80) ? (wkvh + (long)r * 256 + kt + cs)
                                : (wqh + (long)(r - 80) * 256 + kt + cs);
      gl_lds16(src, sm + WOFF + e);
    }
    __syncthreads();
    __builtin_amdgcn_s_setprio(1);
#pragma unroll
    for (int kk = 0; kk < 64; kk += 32) {
      const int csw = (kk + hi * 8) ^ ((lo & 7) << 3);
      bf16x8 bfr[6];
#pragma unroll
      for (int nf = 0; nf < 6; ++nf)
        bfr[nf] = *(const bf16x8*)(sm + WOFF + (nf * 16 + lo) * 64 + csw);
      {
        bf16x8 aqf = *(const bf16x8*)(sm + gr * 64 + ((kk + hi * 8) ^ ((gr & 7) << 3)));
        qacc = __builtin_amdgcn_mfma_f32_16x16x32_bf16(aqf, bfr[5], qacc, 0, 0, 0);
      }
#pragma unroll
      for (int u = 0; u < 3; ++u) {
        const int mf = w + u * 4;
        bf16x8 af = *(const bf16x8*)(sm + (mf * 16 + lo) * 64 + csw);
#pragma unroll
        for (int nf = 0; nf < 5; ++nf)
          acc[u][nf] = __builtin_amdgcn_mfma_f32_16x16x32_bf16(af, bfr[nf], acc[u][nf], 0, 0, 0);
      }
      if (w) {
        bf16x8 af12 = *(const bf16x8*)(sm + (192 + lo) * 64 + csw);
        if (w == 1) {
          acc12a = __builtin_amdgcn_mfma_f32_16x16x32_bf16(af12, bfr[0], acc12a, 0, 0, 0);
          acc12b = __builtin_amdgcn_mfma_f32_16x16x32_bf16(af12, bfr[1], acc12b, 0, 0, 0);
        } else if (w == 2) {
          acc12a = __builtin_amdgcn_mfma_f32_16x16x32_bf16(af12, bfr[2], acc12a, 0, 0, 0);
          acc12b = __builtin_amdgcn_mfma_f32_16x16x32_bf16(af12, bfr[3], acc12b, 0, 0, 0);
        } else {
          acc12a = __builtin_amdgcn_mfma_f32_16x16x32_bf16(af12, bfr[4], acc12a, 0, 0, 0);
        }
      }
    }
    __builtin_amdgcn_s_setprio(0);
  }
  __syncthreads();   // staging dead; aliased K/vT/Q writes may begin

  // ---- phase-1 epilogue: RAW K/V scatter (no BN), Q with folded BN ----
#pragma unroll
  for (int u = 0; u < 3; ++u) {
    const int mf = w + u * 4;
    const int nnb = mf * 16 + hi * 4;
#pragma unroll
    for (int j = 0; j < 4; ++j)
      sm[KOFF + (nnb + j) * KS + lo] = f2bf(acc[u][0][j]);   // K raw, col=lo
#pragma unroll
    for (int nf = 1; nf < 5; ++nf) {
      const int d = nf * 16 - 16 + lo;
      uint2 pp;
      pp.x = (u32)f2bf(acc[u][nf][0]) | ((u32)f2bf(acc[u][nf][1]) << 16);
      pp.y = (u32)f2bf(acc[u][nf][2]) | ((u32)f2bf(acc[u][nf][3]) << 16);
      *(uint2*)(sm + d * VTS + swz(nnb, d)) = pp;            // V raw, packed b64
    }
  }
  {
    const int nnb = 192 + hi * 4;
    if (w == 1) {
#pragma unroll
      for (int j = 0; j < 4; ++j)
        sm[KOFF + (nnb + j) * KS + lo] = f2bf(acc12a[j]);
      const int d = lo;
      uint2 pp;
      pp.x = (u32)f2bf(acc12b[0]) | ((u32)f2bf(acc12b[1]) << 16);
      pp.y = (u32)f2bf(acc12b[2]) | ((u32)f2bf(acc12b[3]) << 16);
      *(uint2*)(sm + d * VTS + swz(nnb, d)) = pp;
    } else if (w == 2) {
      const int d0 = 16 + lo, d1 = 32 + lo;
      uint2 pa, pb;
      pa.x = (u32)f2bf(acc12a[0]) | ((u32)f2bf(acc12a[1]) << 16);
      pa.y = (u32)f2bf(acc12a[2]) | ((u32)f2bf(acc12a[3]) << 16);
      pb.x = (u32)f2bf(acc12b[0]) | ((u32)f2bf(acc12b[1]) << 16);
      pb.y = (u32)f2bf(acc12b[2]) | ((u32)f2bf(acc12b[3]) << 16);
      *(uint2*)(sm + d0 * VTS + swz(nnb, d0)) = pa;
      *(uint2*)(sm + d1 * VTS + swz(nnb, d1)) = pb;
    } else if (w == 3) {
      const int d = 48 + lo;
      uint2 pp;
      pp.x = (u32)f2bf(acc12a[0]) | ((u32)f2bf(acc12a[1]) << 16);
      pp.y = (u32)f2bf(acc12a[2]) | ((u32)f2bf(acc12a[3]) << 16);
      *(uint2*)(sm + d * VTS + swz(nnb, d)) = pp;
    }
  }
  {
    const float s = sqv[hh * 16 + lo], t = tqv[hh * 16 + lo];
#pragma unroll
    for (int j = 0; j < 4; ++j) {
      const int r = w * 16 + hi * 4 + j;
      sm[QOFF + r * QS + lo] = f2bf(qacc[j] * s + t);
    }
  }
  __syncthreads();

  // ---- phase 2: QK^T (scale + K-BN pre-folded into Q; per-q consts cancel) ----
  f32x4 sc[13];
  {
    bf16x8 zf = {0, 0, 0, 0, 0, 0, 0, 0};
    bf16x8 aq2 = zf;
    if (hi < 2) aq2 = *(const bf16x8*)(sm + QOFF + (w * 16 + lo) * QS + hi * 8);
#pragma unroll
    for (int t13 = 0; t13 < 13; ++t13) {
      bf16x8 bk = zf;
      if (hi < 2) bk = *(const bf16x8*)(sm + KOFF + (t13 * 16 + lo) * KS + hi * 8);
      sc[t13] = __builtin_amdgcn_mfma_f32_16x16x32_bf16(aq2, bk, z4, 0, 0, 0);
    }
  }
  __syncthreads();   // all K/Q reads done; P (aliasing K/Q) may be written

  // ---- softmax per C/D row; unnormalized P -> LDS (cols 0..207 all covered) ----
  float rs[4];
#pragma unroll
  for (int j = 0; j < 4; ++j) {
    const int row = w * 16 + hi * 4 + j;
    const int rb = (row < 49) ? row : 0;
    float vals[13];
#pragma unroll
    for (int t = 0; t < 13; ++t) {
      const int col = t * 16 + lo;
      vals[t] = (col < 196) ? sc[t][j] + biasf[(hh * 49 + rb) * 196 + col] : -1e30f;
    }
    float mx = vals[0];
#pragma unroll
    for (int t = 1; t < 13; ++t) mx = fmaxf(mx, vals[t]);
#pragma unroll
    for (int s = 1; s < 16; s <<= 1) mx = fmaxf(mx, __shfl_xor(mx, s, 64));
    float sum = 0.f;
#pragma unroll
    for (int t = 0; t < 13; ++t) { float p = __expf(vals[t] - mx); vals[t] = p; sum += p; }
#pragma unroll
    for (int s = 1; s < 16; s <<= 1) sum += __shfl_xor(sum, s, 64);
#pragma unroll
    for (int t = 0; t < 13; ++t) sm[POFF + row * PS + swz(t * 16 + lo, row)] = f2bf(vals[t]);
    rs[j] = sum;
  }

  // ---- PV: O(64x64) = P(64x208) @ vT-rows; P rows private per wave (no barrier) ----
  f32x4 oacc[4];
#pragma unroll
  for (int n = 0; n < 4; ++n) oacc[n] = z4;
  __builtin_amdgcn_s_setprio(1);
#pragma unroll
  for (int kt = 0; kt < 192; kt += 32) {
    bf16x8 ap = *(const bf16x8*)(sm + POFF + (w * 16 + lo) * PS + ((kt + hi * 8) ^ ((lo & 7) << 3)));
#pragma unroll
    for (int n = 0; n < 4; ++n) {
      bf16x8 bv = *(const bf16x8*)(sm + (n * 16 + lo) * VTS + ((kt + hi * 8) ^ ((lo & 7) << 3)));
      oacc[n] = __builtin_amdgcn_mfma_f32_16x16x32_bf16(ap, bv, oacc[n], 0, 0, 0);
    }
  }
  {  // tail chunk: k = 192..207, 16-wide, hi<2 guarded, no swizzle (identity region)
    bf16x8 zf = {0, 0, 0, 0, 0, 0, 0, 0};
    bf16x8 ap = zf;
    if (hi < 2) ap = *(const bf16x8*)(sm + POFF + (w * 16 + lo) * PS + 192 + hi * 8);
#pragma unroll
    for (int n = 0; n < 4; ++n) {
      bf16x8 bv = zf;
      if (hi < 2) bv = *(const bf16x8*)(sm + (n * 16 + lo) * VTS + 192 + hi * 8);
      oacc[n] = __builtin_amdgcn_mfma_f32_16x16x32_bf16(ap, bv, oacc[n], 0, 0, 0);
    }
  }
  __builtin_amdgcn_s_setprio(0);

  // ---- epilogue: V-BN (raw-V fold: val = O*s_d/rs + t_d), hardswish, store ----
  float svv[4], tvv[4];
#pragma unroll
  for (int n = 0; n < 4; ++n) {
    svv[n] = skv[hh * 80 + 16 + n * 16 + lo];
    tvv[n] = tkv[hh * 80 + 16 + n * 16 + lo];
  }
#pragma unroll
  for (int j = 0; j < 4; ++j) {
    const int row = w * 16 + hi * 4 + j;
    if (row < 49) {
      const float rinv = 1.f / rs[j];
      const long ob = ((long)(bb * 49 + row)) * 1024 + hh * 64 + lo;
#pragma unroll
      for (int n = 0; n < 4; ++n) {
        float val = oacc[n][j] * svv[n] * rinv + tvv[n];
        float hs = val * fminf(fmaxf(val + 3.f, 0.f), 6.f) * (1.f / 6.f);
        osw[ob + n * 16] = f2bf(hs);
      }
    }
  }
}

extern "C" void kernel_launch(void* const* d_in, const int* in_sizes, int n_in,
                              void* d_out, int out_size, void* d_ws, size_t ws_size,
                              hipStream_t stream)
{
  const float* x   = (const float*)d_in[0];
  const float* Wkv = (const float*)d_in[1];
  const float* gkv = (const float*)d_in[2];
  const float* bkv = (const float*)d_in[3];
  const float* mkv = (const float*)d_in[4];
  const float* vkv = (const float*)d_in[5];
  const float* Wq  = (const float*)d_in[6];
  const float* gq  = (const float*)d_in[7];
  const float* bq  = (const float*)d_in[8];
  const float* mq  = (const float*)d_in[9];
  const float* vq  = (const float*)d_in[10];
  const float* Wp  = (const float*)d_in[11];
  const float* gp  = (const float*)d_in[12];
  const float* bp  = (const float*)d_in[13];
  const float* mp  = (const float*)d_in[14];
  const float* vp  = (const float*)d_in[15];
  const float* ab  = (const float*)d_in[16];
  const int* bidx  = (const int*)d_in[17];

  char* ws = (char*)d_ws;
  size_t off = 0;
  auto alloc = [&](size_t bytes) -> char* {
    char* p = ws + off;
    off += (bytes + 255) & ~(size_t)255;
    return p;
  };
  u16* x_bf   = (u16*)alloc((size_t)50176 * 256 * 2);
  u16* wkv_bf = (u16*)alloc((size_t)1280 * 256 * 2);
  u16* wq_bf  = (u16*)alloc((size_t)256 * 256 * 2);
  u16* wp_bf  = (u16*)alloc((size_t)512 * 1024 * 2);
  u16* hsw    = (u16*)alloc((size_t)12544 * 1024 * 2);
  float* bias_f = (float*)alloc((size_t)153664 * 4);
  float* s_kv = (float*)alloc(1280 * 4);
  float* t_kv = (float*)alloc(1280 * 4);
  float* s_q  = (float*)alloc(256 * 4);
  float* t_q  = (float*)alloc(256 * 4);
  float* s_p  = (float*)alloc(512 * 4);
  float* t_p  = (float*)alloc(512 * 4);
  if (off > ws_size) return;  // clean failure instead of OOB writes

  prep_misc<<<4193, 256, 0, stream>>>(Wkv, Wq, Wp, gkv, bkv, mkv, vkv,
                                      gq, bq, mq, vq, gp, bp, mp, vp,
                                      ab, bidx, wkv_bf, wq_bf, wp_bf,
                                      s_kv, t_kv, s_q, t_q, s_p, t_p, bias_f);
  conv_x<<<12544, 256, 0, stream>>>(x, x_bf);
  // fused kv+q+attention: 4096 blocks = 8 XCD chunks x 512 (32 images x 16 heads)
  fused_attn<<<4096, 256, 0, stream>>>(x_bf, wkv_bf, wq_bf, s_kv, t_kv, s_q, t_q, bias_f, hsw);
  // p-proj: M=12544 (98 m-blocks), N=512 (4 n-blocks), XCD-chunked 1D grid
  gemm_bn<<<392, 256, 0, stream>>>(hsw, wp_bf, s_p, t_p, (float*)d_out, 512, 1024, 4);
}